// Round 13
// baseline (290.347 us; speedup 1.0000x reference)
//
#include <hip/hip_runtime.h>

static constexpr int BLK = 256;
static constexpr int BLKA = 128;     // k_agg block size
static constexpr int CHUNK = 4096;   // edges per hist/bin block
static constexpr int BSHIFT = 7;     // 128 dst-nodes per bucket
static constexpr int BNODES = 128;
static constexpr int MAXNB = 1024;

typedef unsigned uv2 __attribute__((ext_vector_type(2)));
typedef unsigned uv4 __attribute__((ext_vector_type(4)));
typedef int iv4 __attribute__((ext_vector_type(4)));

__device__ __forceinline__ float bf_lo(unsigned u) { return __uint_as_float(u << 16); }
__device__ __forceinline__ float bf_hi(unsigned u) { return __uint_as_float(u & 0xFFFF0000u); }
__device__ __forceinline__ unsigned bf_r(float f) {
    unsigned x = __float_as_uint(f);
    x += 0x7fffu + ((x >> 16) & 1u);   // round-to-nearest-even
    return x >> 16;
}
__device__ __forceinline__ unsigned bf_pack(float lo, float hi) {
    return bf_r(lo) | (bf_r(hi) << 16);
}

// non-temporal (evict-first) accessors for single-use streams
__device__ __forceinline__ uv4 ntl4u(const unsigned* p) { return __builtin_nontemporal_load((const uv4*)p); }
__device__ __forceinline__ iv4 ntl4i(const int* p) { return __builtin_nontemporal_load((const iv4*)p); }
__device__ __forceinline__ unsigned ntl1u(const unsigned* p) { return __builtin_nontemporal_load(p); }
__device__ __forceinline__ int ntl1i(const int* p) { return __builtin_nontemporal_load(p); }
__device__ __forceinline__ void nts1u(unsigned v, unsigned* p) { __builtin_nontemporal_store(v, p); }

// ---------------- bucket build ----------------

__global__ __launch_bounds__(BLK) void k_hist(const int* __restrict__ dst, int* __restrict__ ghist,
                                              int e, int NB, int NBLK) {
    __shared__ int h[MAXNB];
    for (int i = threadIdx.x; i < NB; i += BLK) h[i] = 0;
    __syncthreads();
    int base = blockIdx.x * CHUNK;
    int lim = min(e - base, CHUNK);
    bool v4 = ((((size_t)(dst + base)) & 15) == 0);
    if (v4 && lim == CHUNK) {
        for (int q = threadIdx.x; q < CHUNK / 4; q += BLK) {
            iv4 v = ntl4i(dst + base + 4 * q);
            atomicAdd(&h[v.x >> BSHIFT], 1);
            atomicAdd(&h[v.y >> BSHIFT], 1);
            atomicAdd(&h[v.z >> BSHIFT], 1);
            atomicAdd(&h[v.w >> BSHIFT], 1);
        }
    } else {
        for (int r = threadIdx.x; r < lim; r += BLK) atomicAdd(&h[ntl1i(dst + base + r) >> BSHIFT], 1);
    }
    __syncthreads();
    for (int b = threadIdx.x; b < NB; b += BLK) ghist[b * NBLK + blockIdx.x] = h[b];
}

__global__ void k_scan1(const int* __restrict__ in, int* __restrict__ excl,
                        int* __restrict__ partials, int n) {
    __shared__ int s[BLK];
    int i = blockIdx.x * BLK + threadIdx.x;
    int v = (i < n) ? in[i] : 0;
    s[threadIdx.x] = v;
    __syncthreads();
    for (int off = 1; off < BLK; off <<= 1) {
        int t = ((int)threadIdx.x >= off) ? s[threadIdx.x - off] : 0;
        __syncthreads();
        s[threadIdx.x] += t;
        __syncthreads();
    }
    if (i < n) excl[i] = s[threadIdx.x] - v;
    if (threadIdx.x == BLK - 1) partials[blockIdx.x] = s[BLK - 1];
}

__global__ void k_scan2(int* __restrict__ partials, int P) {
    __shared__ int s[1024];
    int carry = 0;
    for (int base = 0; base < P; base += 1024) {
        int i = base + (int)threadIdx.x;
        int v = (i < P) ? partials[i] : 0;
        s[threadIdx.x] = v;
        __syncthreads();
        for (int off = 1; off < 1024; off <<= 1) {
            int t = ((int)threadIdx.x >= off) ? s[threadIdx.x - off] : 0;
            __syncthreads();
            s[threadIdx.x] += t;
            __syncthreads();
        }
        if (i < P) partials[i] = carry + s[threadIdx.x] - v;
        carry += s[1023];
        __syncthreads();
    }
}

__global__ void k_scan3(int* __restrict__ excl, const int* __restrict__ partials, int n) {
    int i = blockIdx.x * BLK + threadIdx.x;
    if (i < n) excl[i] += partials[blockIdx.x];
}

// LDS-staged multisplit: bin edges by dst bucket, coalesced run writes.
// key = src | (dst&127)<<20   (requires n < 2^20)
__global__ __launch_bounds__(BLK) void k_bin(const int* __restrict__ src, const int* __restrict__ dst,
                                             const int* __restrict__ goff, unsigned int* __restrict__ keys,
                                             int e, int NB, int NBLK) {
    __shared__ int hcur[MAXNB];
    __shared__ int sstart[MAXNB + 1];
    __shared__ unsigned int stage[CHUNK];
    __shared__ unsigned short bkt[CHUNK];
    for (int i = threadIdx.x; i < NB; i += BLK) hcur[i] = 0;
    __syncthreads();
    int base = blockIdx.x * CHUNK;
    int lim = min(e - base, CHUNK);
    bool v4 = ((((size_t)(dst + base)) & 15) == 0) && ((((size_t)(src + base)) & 15) == 0) && (lim == CHUNK);
    if (v4) {
        for (int q = threadIdx.x; q < CHUNK / 4; q += BLK) {
            iv4 v = ntl4i(dst + base + 4 * q);
            atomicAdd(&hcur[v.x >> BSHIFT], 1);
            atomicAdd(&hcur[v.y >> BSHIFT], 1);
            atomicAdd(&hcur[v.z >> BSHIFT], 1);
            atomicAdd(&hcur[v.w >> BSHIFT], 1);
        }
    } else {
        for (int r = threadIdx.x; r < lim; r += BLK) atomicAdd(&hcur[ntl1i(dst + base + r) >> BSHIFT], 1);
    }
    __syncthreads();
    for (int i = threadIdx.x; i < MAXNB; i += BLK) sstart[i] = (i < NB) ? hcur[i] : 0;
    __syncthreads();
    for (int off = 1; off < MAXNB; off <<= 1) {
        int tv[MAXNB / BLK];
#pragma unroll
        for (int j = 0; j < MAXNB / BLK; ++j) {
            int i = (int)threadIdx.x + j * BLK;
            tv[j] = (i >= off) ? sstart[i - off] : 0;
        }
        __syncthreads();
#pragma unroll
        for (int j = 0; j < MAXNB / BLK; ++j) sstart[(int)threadIdx.x + j * BLK] += tv[j];
        __syncthreads();
    }
    int ex[MAXNB / BLK];
#pragma unroll
    for (int j = 0; j < MAXNB / BLK; ++j) {
        int i = (int)threadIdx.x + j * BLK;
        ex[j] = sstart[i] - ((i < NB) ? hcur[i] : 0);
    }
    __syncthreads();
#pragma unroll
    for (int j = 0; j < MAXNB / BLK; ++j) {
        int i = (int)threadIdx.x + j * BLK;
        sstart[i] = ex[j];
        if (i < NB) hcur[i] = ex[j];
    }
    __syncthreads();
    if (v4) {
        for (int q = threadIdx.x; q < CHUNK / 4; q += BLK) {
            iv4 sv = ntl4i(src + base + 4 * q);
            iv4 dv = ntl4i(dst + base + 4 * q);
#pragma unroll
            for (int u = 0; u < 4; ++u) {
                int s = (u == 0) ? sv.x : (u == 1) ? sv.y : (u == 2) ? sv.z : sv.w;
                int d = (u == 0) ? dv.x : (u == 1) ? dv.y : (u == 2) ? dv.z : dv.w;
                int b = d >> BSHIFT;
                int pos = atomicAdd(&hcur[b], 1);
                stage[pos] = (unsigned)s | ((unsigned)(d & (BNODES - 1)) << 20);
                bkt[pos] = (unsigned short)b;
            }
        }
    } else {
        for (int r = threadIdx.x; r < lim; r += BLK) {
            int s = src[base + r], d = dst[base + r];
            int b = d >> BSHIFT;
            int pos = atomicAdd(&hcur[b], 1);
            stage[pos] = (unsigned)s | ((unsigned)(d & (BNODES - 1)) << 20);
            bkt[pos] = (unsigned short)b;
        }
    }
    __syncthreads();
    for (int j = threadIdx.x; j < lim; j += BLK) {
        int b = bkt[j];
        nts1u(stage[j], &keys[goff[b * NBLK + blockIdx.x] + (j - sstart[b])]);
    }
}

// per-bucket: node degrees -> dis + node offsets; counting-sort keys -> dst-sorted src CSR
__global__ __launch_bounds__(BLK) void k_sortb(const unsigned int* __restrict__ keys,
                                               const int* __restrict__ goff,
                                               unsigned int* __restrict__ sorted,
                                               int* __restrict__ node_off, float* __restrict__ dis,
                                               int n, int NB, int NBLK, int e) {
    __shared__ int cnt[BNODES];
    __shared__ int sc[BNODES];
    __shared__ int cur[BNODES];
    int b = blockIdx.x;
    int start = goff[b * NBLK];
    int end = (b + 1 < NB) ? goff[(b + 1) * NBLK] : e;
    if (threadIdx.x < BNODES) cnt[threadIdx.x] = 0;
    __syncthreads();
    int astart = (start + 3) & ~3;
    if (astart > end) astart = end;
    int nq = (end - astart) >> 2;
    for (int k = start + (int)threadIdx.x; k < astart; k += BLK) atomicAdd(&cnt[ntl1u(keys + k) >> 20], 1);
    for (int q = threadIdx.x; q < nq; q += BLK) {
        uv4 v = ntl4u(keys + astart + 4 * q);
        atomicAdd(&cnt[v.x >> 20], 1);
        atomicAdd(&cnt[v.y >> 20], 1);
        atomicAdd(&cnt[v.z >> 20], 1);
        atomicAdd(&cnt[v.w >> 20], 1);
    }
    for (int k = astart + (nq << 2) + (int)threadIdx.x; k < end; k += BLK) atomicAdd(&cnt[ntl1u(keys + k) >> 20], 1);
    __syncthreads();
    if (threadIdx.x < BNODES) sc[threadIdx.x] = cnt[threadIdx.x];
    __syncthreads();
    for (int off = 1; off < BNODES; off <<= 1) {
        int v = ((int)threadIdx.x < BNODES && (int)threadIdx.x >= off) ? sc[threadIdx.x - off] : 0;
        __syncthreads();
        if ((int)threadIdx.x < BNODES) sc[threadIdx.x] += v;
        __syncthreads();
    }
    if ((int)threadIdx.x < BNODES) {
        int excl = sc[threadIdx.x] - cnt[threadIdx.x];
        cur[threadIdx.x] = start + excl;
        int d = b * BNODES + (int)threadIdx.x;
        if (d < n) {
            node_off[d] = start + excl;
            dis[d] = rsqrtf(1.0f + (float)cnt[threadIdx.x]);
        }
    }
    if (b == NB - 1 && threadIdx.x == 0) node_off[n] = e;
    __syncthreads();
    for (int k = start + (int)threadIdx.x; k < astart; k += BLK) {
        unsigned key = ntl1u(keys + k);
        int pos = atomicAdd(&cur[key >> 20], 1);
        nts1u(key & 0xFFFFFu, &sorted[pos]);
    }
    for (int q = threadIdx.x; q < nq; q += BLK) {
        uv4 v = ntl4u(keys + astart + 4 * q);
#pragma unroll
        for (int u = 0; u < 4; ++u) {
            unsigned key = (u == 0) ? v.x : (u == 1) ? v.y : (u == 2) ? v.z : v.w;
            int pos = atomicAdd(&cur[key >> 20], 1);
            nts1u(key & 0xFFFFFu, &sorted[pos]);
        }
    }
    for (int k = astart + (nq << 2) + (int)threadIdx.x; k < end; k += BLK) {
        unsigned key = ntl1u(keys + k);
        int pos = atomicAdd(&cur[key >> 20], 1);
        nts1u(key & 0xFFFFFu, &sorted[pos]);
    }
}

// ---------------- dense transforms ----------------

// fp32-out variant (fallback path)
template <int CIN, int COUT, bool BIAS, bool RELU_OUT, bool SCALE_OUT>
__global__ void k_transform(const float* __restrict__ in, const float* __restrict__ W,
                            const float* __restrict__ bias, const float* __restrict__ dis,
                            float* __restrict__ out, int n) {
    int t = blockIdx.x * BLK + threadIdx.x;
    int node = t / COUT, c = t % COUT;
    if (node >= n) return;
    const float* row = in + (size_t)node * CIN;
    float acc = BIAS ? bias[c] : 0.0f;
#pragma unroll
    for (int k = 0; k < CIN; ++k) acc = fmaf(row[k], W[k * COUT + c], acc);
    if (RELU_OUT) acc = fmaxf(acc, 0.0f);
    if (SCALE_OUT) acc *= dis[node];
    out[t] = acc;
}

// packed-bf16 L1 transform: word j of node = channels 2j,2j+1 of (x@W1)*dis
__global__ void k_transform1_bf(const float* __restrict__ in, const float* __restrict__ W,
                                const float* __restrict__ dis, unsigned* __restrict__ out, int n) {
    int t = blockIdx.x * BLK + threadIdx.x;
    int node = t >> 3, j = t & 7;
    if (node >= n) return;
    const float* row = in + (size_t)node * 32;
    float a0 = 0.0f, a1 = 0.0f;
#pragma unroll
    for (int k = 0; k < 32; ++k) {
        float v = row[k];
        a0 = fmaf(v, W[k * 16 + 2 * j], a0);
        a1 = fmaf(v, W[k * 16 + 2 * j + 1], a1);
    }
    float sd = dis[node];
    out[t] = bf_pack(a0 * sd, a1 * sd);
}

// ---------------- fused gather aggregation (4 lanes/node, uv2 gathers, 16-deep MLP) ----
// lane j (0..3) holds channels 4j..4j+3. Index stream is non-temporal (evict-first) so the
// 3.2MB feature buffer stays L2-resident per XCD; feature gathers use normal caching.
// WMODE 0: out = pack( dis*relu(b1 + dis*acc) )
// WMODE 1: out = pack( dis * ((relu((dis*acc)@W2 + b2)) @ W3) )
// WMODE 2: h3 = b3 + dis*acc; partials[block] = sum relu(h3)@Wfc + bfc   (no atomics)
template <int WMODE>
__global__ __launch_bounds__(BLKA) void k_agg(const unsigned* __restrict__ in, const float* __restrict__ dis,
                                              const float* __restrict__ bias,
                                              const float* __restrict__ W2, const float* __restrict__ b2,
                                              const float* __restrict__ W3,
                                              const float* __restrict__ Wfc, const float* __restrict__ bfc,
                                              const unsigned int* __restrict__ sorted,
                                              const int* __restrict__ node_off,
                                              void* __restrict__ outv, int n) {
    int t = blockIdx.x * BLKA + threadIdx.x;
    int d = t >> 2, j = t & 3;
    bool valid = d < n;
    int dd = valid ? d : 0;
    int k = ntl1i(node_off + dd), end = ntl1i(node_off + dd + 1);
    if (!valid) end = k;
    const uv2* inrow = (const uv2*)in;   // row s starts at uv2 index (s<<2)
    uv2 ws = valid ? inrow[((size_t)dd << 2) + j] : (uv2)(0u);   // self-loop term
    float a00 = bf_lo(ws.x), a10 = bf_hi(ws.x), a20 = bf_lo(ws.y), a30 = bf_hi(ws.y);
    float a01 = 0.0f, a11 = 0.0f, a21 = 0.0f, a31 = 0.0f;
    // peel to 16B alignment of sorted+k
    for (; k < end && (k & 3); ++k) {
        uv2 w = inrow[((size_t)ntl1u(sorted + k) << 2) + j];
        a00 += bf_lo(w.x); a10 += bf_hi(w.x); a20 += bf_lo(w.y); a30 += bf_hi(w.y);
    }
    // 16-edge main loop: all 16 gathers in flight before first consume
    for (; k + 15 < end; k += 16) {
        uv4 i0 = ntl4u(sorted + k);
        uv4 i1 = ntl4u(sorted + k + 4);
        uv4 i2 = ntl4u(sorted + k + 8);
        uv4 i3 = ntl4u(sorted + k + 12);
        uv2 w0 = inrow[((size_t)i0.x << 2) + j];
        uv2 w1 = inrow[((size_t)i0.y << 2) + j];
        uv2 w2 = inrow[((size_t)i0.z << 2) + j];
        uv2 w3 = inrow[((size_t)i0.w << 2) + j];
        uv2 w4 = inrow[((size_t)i1.x << 2) + j];
        uv2 w5 = inrow[((size_t)i1.y << 2) + j];
        uv2 w6 = inrow[((size_t)i1.z << 2) + j];
        uv2 w7 = inrow[((size_t)i1.w << 2) + j];
        uv2 w8 = inrow[((size_t)i2.x << 2) + j];
        uv2 w9 = inrow[((size_t)i2.y << 2) + j];
        uv2 wa = inrow[((size_t)i2.z << 2) + j];
        uv2 wb = inrow[((size_t)i2.w << 2) + j];
        uv2 wc = inrow[((size_t)i3.x << 2) + j];
        uv2 wd = inrow[((size_t)i3.y << 2) + j];
        uv2 we = inrow[((size_t)i3.z << 2) + j];
        uv2 wf = inrow[((size_t)i3.w << 2) + j];
        a00 += (bf_lo(w0.x) + bf_lo(w2.x)) + (bf_lo(w4.x) + bf_lo(w6.x));
        a01 += (bf_lo(w1.x) + bf_lo(w3.x)) + (bf_lo(w5.x) + bf_lo(w7.x));
        a10 += (bf_hi(w0.x) + bf_hi(w2.x)) + (bf_hi(w4.x) + bf_hi(w6.x));
        a11 += (bf_hi(w1.x) + bf_hi(w3.x)) + (bf_hi(w5.x) + bf_hi(w7.x));
        a20 += (bf_lo(w0.y) + bf_lo(w2.y)) + (bf_lo(w4.y) + bf_lo(w6.y));
        a21 += (bf_lo(w1.y) + bf_lo(w3.y)) + (bf_lo(w5.y) + bf_lo(w7.y));
        a30 += (bf_hi(w0.y) + bf_hi(w2.y)) + (bf_hi(w4.y) + bf_hi(w6.y));
        a31 += (bf_hi(w1.y) + bf_hi(w3.y)) + (bf_hi(w5.y) + bf_hi(w7.y));
        a00 += (bf_lo(w8.x) + bf_lo(wa.x)) + (bf_lo(wc.x) + bf_lo(we.x));
        a01 += (bf_lo(w9.x) + bf_lo(wb.x)) + (bf_lo(wd.x) + bf_lo(wf.x));
        a10 += (bf_hi(w8.x) + bf_hi(wa.x)) + (bf_hi(wc.x) + bf_hi(we.x));
        a11 += (bf_hi(w9.x) + bf_hi(wb.x)) + (bf_hi(wd.x) + bf_hi(wf.x));
        a20 += (bf_lo(w8.y) + bf_lo(wa.y)) + (bf_lo(wc.y) + bf_lo(we.y));
        a21 += (bf_lo(w9.y) + bf_lo(wb.y)) + (bf_lo(wd.y) + bf_lo(wf.y));
        a30 += (bf_hi(w8.y) + bf_hi(wa.y)) + (bf_hi(wc.y) + bf_hi(we.y));
        a31 += (bf_hi(w9.y) + bf_hi(wb.y)) + (bf_hi(wd.y) + bf_hi(wf.y));
    }
    for (; k + 7 < end; k += 8) {
        uv4 i0 = ntl4u(sorted + k);
        uv4 i1 = ntl4u(sorted + k + 4);
        uv2 w0 = inrow[((size_t)i0.x << 2) + j];
        uv2 w1 = inrow[((size_t)i0.y << 2) + j];
        uv2 w2 = inrow[((size_t)i0.z << 2) + j];
        uv2 w3 = inrow[((size_t)i0.w << 2) + j];
        uv2 w4 = inrow[((size_t)i1.x << 2) + j];
        uv2 w5 = inrow[((size_t)i1.y << 2) + j];
        uv2 w6 = inrow[((size_t)i1.z << 2) + j];
        uv2 w7 = inrow[((size_t)i1.w << 2) + j];
        a00 += (bf_lo(w0.x) + bf_lo(w2.x)) + (bf_lo(w4.x) + bf_lo(w6.x));
        a01 += (bf_lo(w1.x) + bf_lo(w3.x)) + (bf_lo(w5.x) + bf_lo(w7.x));
        a10 += (bf_hi(w0.x) + bf_hi(w2.x)) + (bf_hi(w4.x) + bf_hi(w6.x));
        a11 += (bf_hi(w1.x) + bf_hi(w3.x)) + (bf_hi(w5.x) + bf_hi(w7.x));
        a20 += (bf_lo(w0.y) + bf_lo(w2.y)) + (bf_lo(w4.y) + bf_lo(w6.y));
        a21 += (bf_lo(w1.y) + bf_lo(w3.y)) + (bf_lo(w5.y) + bf_lo(w7.y));
        a30 += (bf_hi(w0.y) + bf_hi(w2.y)) + (bf_hi(w4.y) + bf_hi(w6.y));
        a31 += (bf_hi(w1.y) + bf_hi(w3.y)) + (bf_hi(w5.y) + bf_hi(w7.y));
    }
    for (; k < end; ++k) {
        uv2 w = inrow[((size_t)ntl1u(sorted + k) << 2) + j];
        a00 += bf_lo(w.x); a10 += bf_hi(w.x); a20 += bf_lo(w.y); a30 += bf_hi(w.y);
    }
    float sd = dis[dd];
    float a0 = (a00 + a01) * sd;   // channel 4j
    float a1 = (a10 + a11) * sd;   // channel 4j+1
    float a2 = (a20 + a21) * sd;   // channel 4j+2
    float a3 = (a30 + a31) * sd;   // channel 4j+3

    if (WMODE == 0) {
        uv2* out = (uv2*)outv;
        if (valid) {
            uv2 r;
            r.x = bf_pack(sd * fmaxf(bias[4 * j] + a0, 0.0f), sd * fmaxf(bias[4 * j + 1] + a1, 0.0f));
            r.y = bf_pack(sd * fmaxf(bias[4 * j + 2] + a2, 0.0f), sd * fmaxf(bias[4 * j + 3] + a3, 0.0f));
            out[((size_t)d << 2) + j] = r;
        }
    } else if (WMODE == 1) {
        // h2[32] = relu(A2@W2 + b2); lane j holds h2[j+4p], p=0..7
        float hh[8];
#pragma unroll
        for (int p = 0; p < 8; ++p) hh[p] = b2[j + 4 * p];
#pragma unroll
        for (int kk = 0; kk < 4; ++kk) {
            float r0 = __shfl(a0, kk, 4);   // A2[4kk]
            float r1 = __shfl(a1, kk, 4);   // A2[4kk+1]
            float r2 = __shfl(a2, kk, 4);   // A2[4kk+2]
            float r3 = __shfl(a3, kk, 4);   // A2[4kk+3]
#pragma unroll
            for (int p = 0; p < 8; ++p) {
                int m = j + 4 * p;
                hh[p] = fmaf(r0, W2[(4 * kk) * 32 + m], hh[p]);
                hh[p] = fmaf(r1, W2[(4 * kk + 1) * 32 + m], hh[p]);
                hh[p] = fmaf(r2, W2[(4 * kk + 2) * 32 + m], hh[p]);
                hh[p] = fmaf(r3, W2[(4 * kk + 3) * 32 + m], hh[p]);
            }
        }
#pragma unroll
        for (int p = 0; p < 8; ++p) hh[p] = fmaxf(hh[p], 0.0f);
        float z0 = 0.0f, z1 = 0.0f, z2 = 0.0f, z3 = 0.0f;
#pragma unroll
        for (int kk = 0; kk < 4; ++kk) {
#pragma unroll
            for (int p = 0; p < 8; ++p) {
                float u = __shfl(hh[p], kk, 4);   // h2[kk+4p]
                int m = kk + 4 * p;
                z0 = fmaf(u, W3[m * 16 + 4 * j], z0);
                z1 = fmaf(u, W3[m * 16 + 4 * j + 1], z1);
                z2 = fmaf(u, W3[m * 16 + 4 * j + 2], z2);
                z3 = fmaf(u, W3[m * 16 + 4 * j + 3], z3);
            }
        }
        uv2* out = (uv2*)outv;
        if (valid) {
            uv2 r;
            r.x = bf_pack(z0 * sd, z1 * sd);
            r.y = bf_pack(z2 * sd, z3 * sd);
            out[((size_t)d << 2) + j] = r;
        }
    } else {
        float* partials = (float*)outv;
        float contrib = 0.0f;
        if (valid) {
            contrib = bfc[0] * 0.25f;
            contrib = fmaf(fmaxf(bias[4 * j] + a0, 0.0f), Wfc[4 * j], contrib);
            contrib = fmaf(fmaxf(bias[4 * j + 1] + a1, 0.0f), Wfc[4 * j + 1], contrib);
            contrib = fmaf(fmaxf(bias[4 * j + 2] + a2, 0.0f), Wfc[4 * j + 2], contrib);
            contrib = fmaf(fmaxf(bias[4 * j + 3] + a3, 0.0f), Wfc[4 * j + 3], contrib);
        }
#pragma unroll
        for (int m = 1; m < 64; m <<= 1) contrib += __shfl_xor(contrib, m, 64);
        __shared__ float sw[BLKA / 64];
        if ((threadIdx.x & 63) == 0) sw[threadIdx.x >> 6] = contrib;
        __syncthreads();
        if (threadIdx.x == 0) {
            float tt = 0.0f;
#pragma unroll
            for (int w = 0; w < BLKA / 64; ++w) tt += sw[w];
            partials[blockIdx.x] = tt;
        }
    }
}

// deterministic single-block reduction of partials -> out[0] = sum * inv_n
__global__ __launch_bounds__(BLK) void k_reduce(const float* __restrict__ partials, int P,
                                                float* __restrict__ out, float inv_n) {
    float v = 0.0f;
    for (int i = threadIdx.x; i < P; i += BLK) v += partials[i];
#pragma unroll
    for (int m = 1; m < 64; m <<= 1) v += __shfl_xor(v, m, 64);
    __shared__ float sw[BLK / 64];
    if ((threadIdx.x & 63) == 0) sw[threadIdx.x >> 6] = v;
    __syncthreads();
    if (threadIdx.x == 0) {
        float tt = 0.0f;
#pragma unroll
        for (int w = 0; w < BLK / 64; ++w) tt += sw[w];
        out[0] = tt * inv_n;
    }
}

// ---------------- fallback (atomic scatter, fp32) ----------------

__global__ void k_deg_init(float* __restrict__ deg, int n) {
    int i = blockIdx.x * BLK + threadIdx.x;
    if (i < n) deg[i] = 1.0f;
}
__global__ void k_deg_count(const int* __restrict__ dst, float* __restrict__ deg, int e) {
    int i = blockIdx.x * BLK + threadIdx.x;
    if (i < e) atomicAdd(&deg[dst[i]], 1.0f);
}
__global__ void k_deg_rsqrt(float* __restrict__ deg, int n) {
    int i = blockIdx.x * BLK + threadIdx.x;
    if (i < n) deg[i] = rsqrtf(deg[i]);
}
template <int C, bool RELU_IN, bool BIAS>
__global__ void k_selfloop(const float* __restrict__ h, const float* __restrict__ dis,
                           const float* __restrict__ b, float* __restrict__ agg, int n) {
    int t = blockIdx.x * BLK + threadIdx.x;
    int node = t / C, c = t % C;
    if (node >= n) return;
    float w = dis[node];
    float v = h[t];
    if (RELU_IN) v = fmaxf(v, 0.0f);
    agg[t] = (BIAS ? b[c] : 0.0f) + v * w * w;
}
template <int C, bool RELU_IN>
__global__ void k_scatter(const int* __restrict__ src, const int* __restrict__ dst,
                          const float* __restrict__ h, const float* __restrict__ dis,
                          float* __restrict__ agg, int e) {
    int t = blockIdx.x * BLK + threadIdx.x;
    int edge = t / C, c = t % C;
    if (edge >= e) return;
    int s = src[edge], d = dst[edge];
    float w = dis[s] * dis[d];
    float v = h[(size_t)s * C + c];
    if (RELU_IN) v = fmaxf(v, 0.0f);
    atomicAdd(&agg[(size_t)d * C + c], v * w);
}
__global__ void k_zero(float* __restrict__ out) { out[0] = 0.0f; }
__global__ void k_final(const float* __restrict__ h, const float* __restrict__ Wfc,
                        const float* __restrict__ bfc, float* __restrict__ out, int n,
                        float inv_n) {
    int i = blockIdx.x * BLK + threadIdx.x;
    float v = 0.0f;
    if (i < n) {
        float acc = bfc[0];
        const float* row = h + (size_t)i * 16;
#pragma unroll
        for (int c = 0; c < 16; ++c) acc = fmaf(fmaxf(row[c], 0.0f), Wfc[c], acc);
        v = acc;
    }
#pragma unroll
    for (int off = 32; off > 0; off >>= 1) v += __shfl_down(v, off);
    __shared__ float sw[BLK / 64];
    int wid = threadIdx.x >> 6;
    if ((threadIdx.x & 63) == 0) sw[wid] = v;
    __syncthreads();
    if (threadIdx.x == 0) {
        float t = 0.0f;
#pragma unroll
        for (int w = 0; w < BLK / 64; ++w) t += sw[w];
        atomicAdd(out, t * inv_n);
    }
}

// ---------------- launch ----------------

extern "C" void kernel_launch(void* const* d_in, const int* in_sizes, int n_in,
                              void* d_out, int out_size, void* d_ws, size_t ws_size,
                              hipStream_t stream) {
    const float* x   = (const float*)d_in[0];
    const int* ei    = (const int*)d_in[1];   // integer inputs delivered as int32
    const float* W1  = (const float*)d_in[2];
    const float* b1  = (const float*)d_in[3];
    const float* W2  = (const float*)d_in[4];
    const float* b2  = (const float*)d_in[5];
    const float* W3  = (const float*)d_in[6];
    const float* b3  = (const float*)d_in[7];
    const float* Wfc = (const float*)d_in[8];
    const float* bfc = (const float*)d_in[9];
    float* out = (float*)d_out;

    const int n = in_sizes[0] / 32;
    const int e = in_sizes[1] / 2;
    const int* src = ei;
    const int* dst = ei + e;

    auto g1 = [](long long work) { return dim3((unsigned)((work + BLK - 1) / BLK)); };
    auto gA = [](long long work) { return dim3((unsigned)((work + BLKA - 1) / BLKA)); };

    const int NB   = (n + BNODES - 1) >> BSHIFT;        // dst buckets
    const int NBLK = (e + CHUNK - 1) / CHUNK;           // hist/bin blocks
    const long long L = (long long)NB * NBLK;           // histogram size
    const int P = (int)((L + BLK - 1) / BLK);           // scan partials
    const int PM = (int)(((long long)n * 4 + BLKA - 1) / BLKA);  // mean partial blocks

    auto align_up = [](size_t v) { return (v + 255) & ~(size_t)255; };
    size_t off = 0;
    auto carve = [&](size_t bytes) { size_t o = off; off += align_up(bytes); return o; };
    char* base = (char*)d_ws;
    size_t o_dis   = carve((size_t)n * 4);
    size_t o_noff  = carve(((size_t)n + 1) * 4);
    size_t o_ghist = carve((size_t)L * 4);
    size_t o_goff  = carve((size_t)L * 4);
    size_t o_part  = carve(((size_t)P + 1) * 4);
    size_t o_pm    = carve((size_t)PM * 4);
    size_t o_A     = carve((size_t)n * 16 * 2);
    size_t o_B     = carve((size_t)n * 16 * 2);
    size_t o_keys  = carve((size_t)e * 4);
    size_t o_sort  = carve((size_t)e * 4);
    bool ok = (off <= ws_size) && (NB <= MAXNB) && (n < (1 << 20));

    if (ok) {
        float* dis  = (float*)(base + o_dis);
        int* noff   = (int*)(base + o_noff);
        int* ghist  = (int*)(base + o_ghist);
        int* goff   = (int*)(base + o_goff);
        int* part   = (int*)(base + o_part);
        float* pm   = (float*)(base + o_pm);
        unsigned* A = (unsigned*)(base + o_A);
        unsigned* B = (unsigned*)(base + o_B);
        unsigned int* keys   = (unsigned int*)(base + o_keys);
        unsigned int* sorted = (unsigned int*)(base + o_sort);

        // build: hist -> scan -> bin -> per-bucket sort (+ node offsets + dis)
        k_hist<<<dim3(NBLK), BLK, 0, stream>>>(dst, ghist, e, NB, NBLK);
        k_scan1<<<g1(L), BLK, 0, stream>>>(ghist, goff, part, (int)L);
        k_scan2<<<1, 1024, 0, stream>>>(part, P);
        k_scan3<<<g1(L), BLK, 0, stream>>>(goff, part, (int)L);
        k_bin<<<dim3(NBLK), BLK, 0, stream>>>(src, dst, goff, keys, e, NB, NBLK);
        k_sortb<<<dim3(NB), BLK, 0, stream>>>(keys, goff, sorted, noff, dis, n, NB, NBLK, e);

        // L1: A = pack-bf16((x@W1)*dis)
        k_transform1_bf<<<g1((long long)n * 8), BLK, 0, stream>>>(x, W1, dis, A, n);
        // L1 agg: B = pack(dis*relu(b1 + dis*sum))
        k_agg<0><<<gA((long long)n * 4), BLKA, 0, stream>>>(A, dis, b1, nullptr, nullptr, nullptr, nullptr, nullptr,
                                                            sorted, noff, B, n);
        // L2 agg + fused L2/L3 transforms
        k_agg<1><<<gA((long long)n * 4), BLKA, 0, stream>>>(B, dis, nullptr, W2, b2, W3, nullptr, nullptr,
                                                            sorted, noff, A, n);
        // L3 agg + fused FC -> per-block partials -> deterministic reduce
        k_agg<2><<<gA((long long)n * 4), BLKA, 0, stream>>>(A, dis, b3, nullptr, nullptr, nullptr, Wfc, bfc,
                                                            sorted, noff, pm, n);
        k_reduce<<<1, BLK, 0, stream>>>(pm, PM, out, 1.0f / (float)n);
    } else {
        // fallback: atomic scatter path (fp32)
        float* dis = (float*)d_ws;
        float* A = dis + (((size_t)n + 255) & ~(size_t)255);
        float* B = A + (size_t)n * 32;

        k_deg_init<<<g1(n), BLK, 0, stream>>>(dis, n);
        k_deg_count<<<g1(e), BLK, 0, stream>>>(dst, dis, e);
        k_deg_rsqrt<<<g1(n), BLK, 0, stream>>>(dis, n);

        k_transform<32, 16, false, false, false><<<g1((long long)n * 16), BLK, 0, stream>>>(x, W1, nullptr, nullptr, A, n);
        k_selfloop<16, false, true><<<g1((long long)n * 16), BLK, 0, stream>>>(A, dis, b1, B, n);
        k_scatter<16, false><<<g1((long long)e * 16), BLK, 0, stream>>>(src, dst, A, dis, B, e);

        k_selfloop<16, true, false><<<g1((long long)n * 16), BLK, 0, stream>>>(B, dis, nullptr, A, n);
        k_scatter<16, true><<<g1((long long)e * 16), BLK, 0, stream>>>(src, dst, B, dis, A, e);
        k_transform<16, 32, true, true, false><<<g1((long long)n * 32), BLK, 0, stream>>>(A, W2, b2, nullptr, B, n);

        k_transform<32, 16, false, false, false><<<g1((long long)n * 16), BLK, 0, stream>>>(B, W3, nullptr, nullptr, A, n);
        k_selfloop<16, false, true><<<g1((long long)n * 16), BLK, 0, stream>>>(A, dis, b3, B, n);
        k_scatter<16, false><<<g1((long long)e * 16), BLK, 0, stream>>>(src, dst, A, dis, B, e);

        k_zero<<<1, 1, 0, stream>>>(out);
        k_final<<<g1(n), BLK, 0, stream>>>(B, Wfc, bfc, out, n, 1.0f / (float)n);
    }
}

// Round 14
// 213.408 us; speedup vs baseline: 1.3605x; 1.3605x over previous
//
#include <hip/hip_runtime.h>

static constexpr int BLK = 256;
static constexpr int BLKA = 128;     // k_agg block size
static constexpr int CHUNK = 4096;   // edges per hist/bin block
static constexpr int BSHIFT = 7;     // 128 dst-nodes per bucket
static constexpr int BNODES = 128;
static constexpr int MAXNB = 1024;

typedef unsigned uv2 __attribute__((ext_vector_type(2)));
typedef unsigned uv4 __attribute__((ext_vector_type(4)));

__device__ __forceinline__ float bf_lo(unsigned u) { return __uint_as_float(u << 16); }
__device__ __forceinline__ float bf_hi(unsigned u) { return __uint_as_float(u & 0xFFFF0000u); }
__device__ __forceinline__ unsigned bf_r(float f) {
    unsigned x = __float_as_uint(f);
    x += 0x7fffu + ((x >> 16) & 1u);   // round-to-nearest-even
    return x >> 16;
}
__device__ __forceinline__ unsigned bf_pack(float lo, float hi) {
    return bf_r(lo) | (bf_r(hi) << 16);
}

// non-temporal (evict-first) LOADS for the single-use index stream in k_agg only.
// NOTE (round-13 lesson): non-temporal scattered STORES cause ~8x write amplification
// (evict-first defeats L2 write coalescing) — never use them for scattered writes.
__device__ __forceinline__ uv4 ntl4u(const unsigned* p) { return __builtin_nontemporal_load((const uv4*)p); }
__device__ __forceinline__ unsigned ntl1u(const unsigned* p) { return __builtin_nontemporal_load(p); }

// ---------------- bucket build ----------------

__global__ __launch_bounds__(BLK) void k_hist(const int* __restrict__ dst, int* __restrict__ ghist,
                                              int e, int NB, int NBLK) {
    __shared__ int h[MAXNB];
    for (int i = threadIdx.x; i < NB; i += BLK) h[i] = 0;
    __syncthreads();
    int base = blockIdx.x * CHUNK;
    int lim = min(e - base, CHUNK);
    bool v4 = ((((size_t)(dst + base)) & 15) == 0);
    if (v4 && lim == CHUNK) {
        const int4* d4 = (const int4*)(dst + base);
        for (int q = threadIdx.x; q < CHUNK / 4; q += BLK) {
            int4 v = d4[q];
            atomicAdd(&h[v.x >> BSHIFT], 1);
            atomicAdd(&h[v.y >> BSHIFT], 1);
            atomicAdd(&h[v.z >> BSHIFT], 1);
            atomicAdd(&h[v.w >> BSHIFT], 1);
        }
    } else {
        for (int r = threadIdx.x; r < lim; r += BLK) atomicAdd(&h[dst[base + r] >> BSHIFT], 1);
    }
    __syncthreads();
    for (int b = threadIdx.x; b < NB; b += BLK) ghist[b * NBLK + blockIdx.x] = h[b];
}

__global__ void k_scan1(const int* __restrict__ in, int* __restrict__ excl,
                        int* __restrict__ partials, int n) {
    __shared__ int s[BLK];
    int i = blockIdx.x * BLK + threadIdx.x;
    int v = (i < n) ? in[i] : 0;
    s[threadIdx.x] = v;
    __syncthreads();
    for (int off = 1; off < BLK; off <<= 1) {
        int t = ((int)threadIdx.x >= off) ? s[threadIdx.x - off] : 0;
        __syncthreads();
        s[threadIdx.x] += t;
        __syncthreads();
    }
    if (i < n) excl[i] = s[threadIdx.x] - v;
    if (threadIdx.x == BLK - 1) partials[blockIdx.x] = s[BLK - 1];
}

__global__ void k_scan2(int* __restrict__ partials, int P) {
    __shared__ int s[1024];
    int carry = 0;
    for (int base = 0; base < P; base += 1024) {
        int i = base + (int)threadIdx.x;
        int v = (i < P) ? partials[i] : 0;
        s[threadIdx.x] = v;
        __syncthreads();
        for (int off = 1; off < 1024; off <<= 1) {
            int t = ((int)threadIdx.x >= off) ? s[threadIdx.x - off] : 0;
            __syncthreads();
            s[threadIdx.x] += t;
            __syncthreads();
        }
        if (i < P) partials[i] = carry + s[threadIdx.x] - v;
        carry += s[1023];
        __syncthreads();
    }
}

__global__ void k_scan3(int* __restrict__ excl, const int* __restrict__ partials, int n) {
    int i = blockIdx.x * BLK + threadIdx.x;
    if (i < n) excl[i] += partials[blockIdx.x];
}

// LDS-staged multisplit: bin edges by dst bucket, coalesced run writes.
// key = src | (dst&127)<<20   (requires n < 2^20)
__global__ __launch_bounds__(BLK) void k_bin(const int* __restrict__ src, const int* __restrict__ dst,
                                             const int* __restrict__ goff, unsigned int* __restrict__ keys,
                                             int e, int NB, int NBLK) {
    __shared__ int hcur[MAXNB];
    __shared__ int sstart[MAXNB + 1];
    __shared__ unsigned int stage[CHUNK];
    __shared__ unsigned short bkt[CHUNK];
    for (int i = threadIdx.x; i < NB; i += BLK) hcur[i] = 0;
    __syncthreads();
    int base = blockIdx.x * CHUNK;
    int lim = min(e - base, CHUNK);
    bool v4 = ((((size_t)(dst + base)) & 15) == 0) && ((((size_t)(src + base)) & 15) == 0) && (lim == CHUNK);
    if (v4) {
        const int4* d4 = (const int4*)(dst + base);
        for (int q = threadIdx.x; q < CHUNK / 4; q += BLK) {
            int4 v = d4[q];
            atomicAdd(&hcur[v.x >> BSHIFT], 1);
            atomicAdd(&hcur[v.y >> BSHIFT], 1);
            atomicAdd(&hcur[v.z >> BSHIFT], 1);
            atomicAdd(&hcur[v.w >> BSHIFT], 1);
        }
    } else {
        for (int r = threadIdx.x; r < lim; r += BLK) atomicAdd(&hcur[dst[base + r] >> BSHIFT], 1);
    }
    __syncthreads();
    for (int i = threadIdx.x; i < MAXNB; i += BLK) sstart[i] = (i < NB) ? hcur[i] : 0;
    __syncthreads();
    for (int off = 1; off < MAXNB; off <<= 1) {
        int tv[MAXNB / BLK];
#pragma unroll
        for (int j = 0; j < MAXNB / BLK; ++j) {
            int i = (int)threadIdx.x + j * BLK;
            tv[j] = (i >= off) ? sstart[i - off] : 0;
        }
        __syncthreads();
#pragma unroll
        for (int j = 0; j < MAXNB / BLK; ++j) sstart[(int)threadIdx.x + j * BLK] += tv[j];
        __syncthreads();
    }
    int ex[MAXNB / BLK];
#pragma unroll
    for (int j = 0; j < MAXNB / BLK; ++j) {
        int i = (int)threadIdx.x + j * BLK;
        ex[j] = sstart[i] - ((i < NB) ? hcur[i] : 0);
    }
    __syncthreads();
#pragma unroll
    for (int j = 0; j < MAXNB / BLK; ++j) {
        int i = (int)threadIdx.x + j * BLK;
        sstart[i] = ex[j];
        if (i < NB) hcur[i] = ex[j];
    }
    __syncthreads();
    if (v4) {
        const int4* s4 = (const int4*)(src + base);
        const int4* d4 = (const int4*)(dst + base);
        for (int q = threadIdx.x; q < CHUNK / 4; q += BLK) {
            int4 sv = s4[q];
            int4 dv = d4[q];
#pragma unroll
            for (int u = 0; u < 4; ++u) {
                int s = (u == 0) ? sv.x : (u == 1) ? sv.y : (u == 2) ? sv.z : sv.w;
                int d = (u == 0) ? dv.x : (u == 1) ? dv.y : (u == 2) ? dv.z : dv.w;
                int b = d >> BSHIFT;
                int pos = atomicAdd(&hcur[b], 1);
                stage[pos] = (unsigned)s | ((unsigned)(d & (BNODES - 1)) << 20);
                bkt[pos] = (unsigned short)b;
            }
        }
    } else {
        for (int r = threadIdx.x; r < lim; r += BLK) {
            int s = src[base + r], d = dst[base + r];
            int b = d >> BSHIFT;
            int pos = atomicAdd(&hcur[b], 1);
            stage[pos] = (unsigned)s | ((unsigned)(d & (BNODES - 1)) << 20);
            bkt[pos] = (unsigned short)b;
        }
    }
    __syncthreads();
    for (int j = threadIdx.x; j < lim; j += BLK) {
        int b = bkt[j];
        keys[goff[b * NBLK + blockIdx.x] + (j - sstart[b])] = stage[j];
    }
}

// per-bucket: node degrees -> dis + node offsets; counting-sort keys -> dst-sorted src CSR
__global__ __launch_bounds__(BLK) void k_sortb(const unsigned int* __restrict__ keys,
                                               const int* __restrict__ goff,
                                               unsigned int* __restrict__ sorted,
                                               int* __restrict__ node_off, float* __restrict__ dis,
                                               int n, int NB, int NBLK, int e) {
    __shared__ int cnt[BNODES];
    __shared__ int sc[BNODES];
    __shared__ int cur[BNODES];
    int b = blockIdx.x;
    int start = goff[b * NBLK];
    int end = (b + 1 < NB) ? goff[(b + 1) * NBLK] : e;
    if (threadIdx.x < BNODES) cnt[threadIdx.x] = 0;
    __syncthreads();
    int astart = (start + 3) & ~3;
    if (astart > end) astart = end;
    int nq = (end - astart) >> 2;
    for (int k = start + (int)threadIdx.x; k < astart; k += BLK) atomicAdd(&cnt[keys[k] >> 20], 1);
    {
        const uint4* k4 = (const uint4*)(keys + astart);
        for (int q = threadIdx.x; q < nq; q += BLK) {
            uint4 v = k4[q];
            atomicAdd(&cnt[v.x >> 20], 1);
            atomicAdd(&cnt[v.y >> 20], 1);
            atomicAdd(&cnt[v.z >> 20], 1);
            atomicAdd(&cnt[v.w >> 20], 1);
        }
    }
    for (int k = astart + (nq << 2) + (int)threadIdx.x; k < end; k += BLK) atomicAdd(&cnt[keys[k] >> 20], 1);
    __syncthreads();
    if (threadIdx.x < BNODES) sc[threadIdx.x] = cnt[threadIdx.x];
    __syncthreads();
    for (int off = 1; off < BNODES; off <<= 1) {
        int v = ((int)threadIdx.x < BNODES && (int)threadIdx.x >= off) ? sc[threadIdx.x - off] : 0;
        __syncthreads();
        if ((int)threadIdx.x < BNODES) sc[threadIdx.x] += v;
        __syncthreads();
    }
    if ((int)threadIdx.x < BNODES) {
        int excl = sc[threadIdx.x] - cnt[threadIdx.x];
        cur[threadIdx.x] = start + excl;
        int d = b * BNODES + (int)threadIdx.x;
        if (d < n) {
            node_off[d] = start + excl;
            dis[d] = rsqrtf(1.0f + (float)cnt[threadIdx.x]);
        }
    }
    if (b == NB - 1 && threadIdx.x == 0) node_off[n] = e;
    __syncthreads();
    for (int k = start + (int)threadIdx.x; k < astart; k += BLK) {
        unsigned key = keys[k];
        int pos = atomicAdd(&cur[key >> 20], 1);
        sorted[pos] = key & 0xFFFFFu;
    }
    {
        const uint4* k4 = (const uint4*)(keys + astart);
        for (int q = threadIdx.x; q < nq; q += BLK) {
            uint4 v = k4[q];
#pragma unroll
            for (int u = 0; u < 4; ++u) {
                unsigned key = (u == 0) ? v.x : (u == 1) ? v.y : (u == 2) ? v.z : v.w;
                int pos = atomicAdd(&cur[key >> 20], 1);
                sorted[pos] = key & 0xFFFFFu;
            }
        }
    }
    for (int k = astart + (nq << 2) + (int)threadIdx.x; k < end; k += BLK) {
        unsigned key = keys[k];
        int pos = atomicAdd(&cur[key >> 20], 1);
        sorted[pos] = key & 0xFFFFFu;
    }
}

// ---------------- dense transforms ----------------

// fp32-out variant (fallback path)
template <int CIN, int COUT, bool BIAS, bool RELU_OUT, bool SCALE_OUT>
__global__ void k_transform(const float* __restrict__ in, const float* __restrict__ W,
                            const float* __restrict__ bias, const float* __restrict__ dis,
                            float* __restrict__ out, int n) {
    int t = blockIdx.x * BLK + threadIdx.x;
    int node = t / COUT, c = t % COUT;
    if (node >= n) return;
    const float* row = in + (size_t)node * CIN;
    float acc = BIAS ? bias[c] : 0.0f;
#pragma unroll
    for (int k = 0; k < CIN; ++k) acc = fmaf(row[k], W[k * COUT + c], acc);
    if (RELU_OUT) acc = fmaxf(acc, 0.0f);
    if (SCALE_OUT) acc *= dis[node];
    out[t] = acc;
}

// packed-bf16 L1 transform: word j of node = channels 2j,2j+1 of (x@W1)*dis
__global__ void k_transform1_bf(const float* __restrict__ in, const float* __restrict__ W,
                                const float* __restrict__ dis, unsigned* __restrict__ out, int n) {
    int t = blockIdx.x * BLK + threadIdx.x;
    int node = t >> 3, j = t & 7;
    if (node >= n) return;
    const float* row = in + (size_t)node * 32;
    float a0 = 0.0f, a1 = 0.0f;
#pragma unroll
    for (int k = 0; k < 32; ++k) {
        float v = row[k];
        a0 = fmaf(v, W[k * 16 + 2 * j], a0);
        a1 = fmaf(v, W[k * 16 + 2 * j + 1], a1);
    }
    float sd = dis[node];
    out[t] = bf_pack(a0 * sd, a1 * sd);
}

// ---------------- fused gather aggregation (4 lanes/node, uv2 gathers, 16-deep MLP) ----
// lane j (0..3) holds channels 4j..4j+3. Index stream loads are non-temporal (evict-first)
// so the 3.2MB feature buffer stays L2-resident; feature gathers use normal caching.
// WMODE 0: out = pack( dis*relu(b1 + dis*acc) )
// WMODE 1: out = pack( dis * ((relu((dis*acc)@W2 + b2)) @ W3) )
// WMODE 2: h3 = b3 + dis*acc; partials[block] = sum relu(h3)@Wfc + bfc   (no atomics)
template <int WMODE>
__global__ __launch_bounds__(BLKA) void k_agg(const unsigned* __restrict__ in, const float* __restrict__ dis,
                                              const float* __restrict__ bias,
                                              const float* __restrict__ W2, const float* __restrict__ b2,
                                              const float* __restrict__ W3,
                                              const float* __restrict__ Wfc, const float* __restrict__ bfc,
                                              const unsigned int* __restrict__ sorted,
                                              const int* __restrict__ node_off,
                                              void* __restrict__ outv, int n) {
    int t = blockIdx.x * BLKA + threadIdx.x;
    int d = t >> 2, j = t & 3;
    bool valid = d < n;
    int dd = valid ? d : 0;
    int k = node_off[dd], end = node_off[dd + 1];
    if (!valid) end = k;
    const uv2* inrow = (const uv2*)in;   // row s starts at uv2 index (s<<2)
    uv2 ws = valid ? inrow[((size_t)dd << 2) + j] : (uv2)(0u);   // self-loop term
    float a00 = bf_lo(ws.x), a10 = bf_hi(ws.x), a20 = bf_lo(ws.y), a30 = bf_hi(ws.y);
    float a01 = 0.0f, a11 = 0.0f, a21 = 0.0f, a31 = 0.0f;
    // peel to 16B alignment of sorted+k
    for (; k < end && (k & 3); ++k) {
        uv2 w = inrow[((size_t)ntl1u(sorted + k) << 2) + j];
        a00 += bf_lo(w.x); a10 += bf_hi(w.x); a20 += bf_lo(w.y); a30 += bf_hi(w.y);
    }
    // 16-edge main loop: all 16 gathers in flight before first consume
    for (; k + 15 < end; k += 16) {
        uv4 i0 = ntl4u(sorted + k);
        uv4 i1 = ntl4u(sorted + k + 4);
        uv4 i2 = ntl4u(sorted + k + 8);
        uv4 i3 = ntl4u(sorted + k + 12);
        uv2 w0 = inrow[((size_t)i0.x << 2) + j];
        uv2 w1 = inrow[((size_t)i0.y << 2) + j];
        uv2 w2 = inrow[((size_t)i0.z << 2) + j];
        uv2 w3 = inrow[((size_t)i0.w << 2) + j];
        uv2 w4 = inrow[((size_t)i1.x << 2) + j];
        uv2 w5 = inrow[((size_t)i1.y << 2) + j];
        uv2 w6 = inrow[((size_t)i1.z << 2) + j];
        uv2 w7 = inrow[((size_t)i1.w << 2) + j];
        uv2 w8 = inrow[((size_t)i2.x << 2) + j];
        uv2 w9 = inrow[((size_t)i2.y << 2) + j];
        uv2 wa = inrow[((size_t)i2.z << 2) + j];
        uv2 wb = inrow[((size_t)i2.w << 2) + j];
        uv2 wc = inrow[((size_t)i3.x << 2) + j];
        uv2 wd = inrow[((size_t)i3.y << 2) + j];
        uv2 we = inrow[((size_t)i3.z << 2) + j];
        uv2 wf = inrow[((size_t)i3.w << 2) + j];
        a00 += (bf_lo(w0.x) + bf_lo(w2.x)) + (bf_lo(w4.x) + bf_lo(w6.x));
        a01 += (bf_lo(w1.x) + bf_lo(w3.x)) + (bf_lo(w5.x) + bf_lo(w7.x));
        a10 += (bf_hi(w0.x) + bf_hi(w2.x)) + (bf_hi(w4.x) + bf_hi(w6.x));
        a11 += (bf_hi(w1.x) + bf_hi(w3.x)) + (bf_hi(w5.x) + bf_hi(w7.x));
        a20 += (bf_lo(w0.y) + bf_lo(w2.y)) + (bf_lo(w4.y) + bf_lo(w6.y));
        a21 += (bf_lo(w1.y) + bf_lo(w3.y)) + (bf_lo(w5.y) + bf_lo(w7.y));
        a30 += (bf_hi(w0.y) + bf_hi(w2.y)) + (bf_hi(w4.y) + bf_hi(w6.y));
        a31 += (bf_hi(w1.y) + bf_hi(w3.y)) + (bf_hi(w5.y) + bf_hi(w7.y));
        a00 += (bf_lo(w8.x) + bf_lo(wa.x)) + (bf_lo(wc.x) + bf_lo(we.x));
        a01 += (bf_lo(w9.x) + bf_lo(wb.x)) + (bf_lo(wd.x) + bf_lo(wf.x));
        a10 += (bf_hi(w8.x) + bf_hi(wa.x)) + (bf_hi(wc.x) + bf_hi(we.x));
        a11 += (bf_hi(w9.x) + bf_hi(wb.x)) + (bf_hi(wd.x) + bf_hi(wf.x));
        a20 += (bf_lo(w8.y) + bf_lo(wa.y)) + (bf_lo(wc.y) + bf_lo(we.y));
        a21 += (bf_lo(w9.y) + bf_lo(wb.y)) + (bf_lo(wd.y) + bf_lo(wf.y));
        a30 += (bf_hi(w8.y) + bf_hi(wa.y)) + (bf_hi(wc.y) + bf_hi(we.y));
        a31 += (bf_hi(w9.y) + bf_hi(wb.y)) + (bf_hi(wd.y) + bf_hi(wf.y));
    }
    for (; k + 7 < end; k += 8) {
        uv4 i0 = ntl4u(sorted + k);
        uv4 i1 = ntl4u(sorted + k + 4);
        uv2 w0 = inrow[((size_t)i0.x << 2) + j];
        uv2 w1 = inrow[((size_t)i0.y << 2) + j];
        uv2 w2 = inrow[((size_t)i0.z << 2) + j];
        uv2 w3 = inrow[((size_t)i0.w << 2) + j];
        uv2 w4 = inrow[((size_t)i1.x << 2) + j];
        uv2 w5 = inrow[((size_t)i1.y << 2) + j];
        uv2 w6 = inrow[((size_t)i1.z << 2) + j];
        uv2 w7 = inrow[((size_t)i1.w << 2) + j];
        a00 += (bf_lo(w0.x) + bf_lo(w2.x)) + (bf_lo(w4.x) + bf_lo(w6.x));
        a01 += (bf_lo(w1.x) + bf_lo(w3.x)) + (bf_lo(w5.x) + bf_lo(w7.x));
        a10 += (bf_hi(w0.x) + bf_hi(w2.x)) + (bf_hi(w4.x) + bf_hi(w6.x));
        a11 += (bf_hi(w1.x) + bf_hi(w3.x)) + (bf_hi(w5.x) + bf_hi(w7.x));
        a20 += (bf_lo(w0.y) + bf_lo(w2.y)) + (bf_lo(w4.y) + bf_lo(w6.y));
        a21 += (bf_lo(w1.y) + bf_lo(w3.y)) + (bf_lo(w5.y) + bf_lo(w7.y));
        a30 += (bf_hi(w0.y) + bf_hi(w2.y)) + (bf_hi(w4.y) + bf_hi(w6.y));
        a31 += (bf_hi(w1.y) + bf_hi(w3.y)) + (bf_hi(w5.y) + bf_hi(w7.y));
    }
    for (; k < end; ++k) {
        uv2 w = inrow[((size_t)ntl1u(sorted + k) << 2) + j];
        a00 += bf_lo(w.x); a10 += bf_hi(w.x); a20 += bf_lo(w.y); a30 += bf_hi(w.y);
    }
    float sd = dis[dd];
    float a0 = (a00 + a01) * sd;   // channel 4j
    float a1 = (a10 + a11) * sd;   // channel 4j+1
    float a2 = (a20 + a21) * sd;   // channel 4j+2
    float a3 = (a30 + a31) * sd;   // channel 4j+3

    if (WMODE == 0) {
        uv2* out = (uv2*)outv;
        if (valid) {
            uv2 r;
            r.x = bf_pack(sd * fmaxf(bias[4 * j] + a0, 0.0f), sd * fmaxf(bias[4 * j + 1] + a1, 0.0f));
            r.y = bf_pack(sd * fmaxf(bias[4 * j + 2] + a2, 0.0f), sd * fmaxf(bias[4 * j + 3] + a3, 0.0f));
            out[((size_t)d << 2) + j] = r;
        }
    } else if (WMODE == 1) {
        // h2[32] = relu(A2@W2 + b2); lane j holds h2[j+4p], p=0..7
        float hh[8];
#pragma unroll
        for (int p = 0; p < 8; ++p) hh[p] = b2[j + 4 * p];
#pragma unroll
        for (int kk = 0; kk < 4; ++kk) {
            float r0 = __shfl(a0, kk, 4);   // A2[4kk]
            float r1 = __shfl(a1, kk, 4);   // A2[4kk+1]
            float r2 = __shfl(a2, kk, 4);   // A2[4kk+2]
            float r3 = __shfl(a3, kk, 4);   // A2[4kk+3]
#pragma unroll
            for (int p = 0; p < 8; ++p) {
                int m = j + 4 * p;
                hh[p] = fmaf(r0, W2[(4 * kk) * 32 + m], hh[p]);
                hh[p] = fmaf(r1, W2[(4 * kk + 1) * 32 + m], hh[p]);
                hh[p] = fmaf(r2, W2[(4 * kk + 2) * 32 + m], hh[p]);
                hh[p] = fmaf(r3, W2[(4 * kk + 3) * 32 + m], hh[p]);
            }
        }
#pragma unroll
        for (int p = 0; p < 8; ++p) hh[p] = fmaxf(hh[p], 0.0f);
        float z0 = 0.0f, z1 = 0.0f, z2 = 0.0f, z3 = 0.0f;
#pragma unroll
        for (int kk = 0; kk < 4; ++kk) {
#pragma unroll
            for (int p = 0; p < 8; ++p) {
                float u = __shfl(hh[p], kk, 4);   // h2[kk+4p]
                int m = kk + 4 * p;
                z0 = fmaf(u, W3[m * 16 + 4 * j], z0);
                z1 = fmaf(u, W3[m * 16 + 4 * j + 1], z1);
                z2 = fmaf(u, W3[m * 16 + 4 * j + 2], z2);
                z3 = fmaf(u, W3[m * 16 + 4 * j + 3], z3);
            }
        }
        uv2* out = (uv2*)outv;
        if (valid) {
            uv2 r;
            r.x = bf_pack(z0 * sd, z1 * sd);
            r.y = bf_pack(z2 * sd, z3 * sd);
            out[((size_t)d << 2) + j] = r;
        }
    } else {
        float* partials = (float*)outv;
        float contrib = 0.0f;
        if (valid) {
            contrib = bfc[0] * 0.25f;
            contrib = fmaf(fmaxf(bias[4 * j] + a0, 0.0f), Wfc[4 * j], contrib);
            contrib = fmaf(fmaxf(bias[4 * j + 1] + a1, 0.0f), Wfc[4 * j + 1], contrib);
            contrib = fmaf(fmaxf(bias[4 * j + 2] + a2, 0.0f), Wfc[4 * j + 2], contrib);
            contrib = fmaf(fmaxf(bias[4 * j + 3] + a3, 0.0f), Wfc[4 * j + 3], contrib);
        }
#pragma unroll
        for (int m = 1; m < 64; m <<= 1) contrib += __shfl_xor(contrib, m, 64);
        __shared__ float sw[BLKA / 64];
        if ((threadIdx.x & 63) == 0) sw[threadIdx.x >> 6] = contrib;
        __syncthreads();
        if (threadIdx.x == 0) {
            float tt = 0.0f;
#pragma unroll
            for (int w = 0; w < BLKA / 64; ++w) tt += sw[w];
            partials[blockIdx.x] = tt;
        }
    }
}

// deterministic single-block reduction of partials -> out[0] = sum * inv_n
__global__ __launch_bounds__(BLK) void k_reduce(const float* __restrict__ partials, int P,
                                                float* __restrict__ out, float inv_n) {
    float v = 0.0f;
    for (int i = threadIdx.x; i < P; i += BLK) v += partials[i];
#pragma unroll
    for (int m = 1; m < 64; m <<= 1) v += __shfl_xor(v, m, 64);
    __shared__ float sw[BLK / 64];
    if ((threadIdx.x & 63) == 0) sw[threadIdx.x >> 6] = v;
    __syncthreads();
    if (threadIdx.x == 0) {
        float tt = 0.0f;
#pragma unroll
        for (int w = 0; w < BLK / 64; ++w) tt += sw[w];
        out[0] = tt * inv_n;
    }
}

// ---------------- fallback (atomic scatter, fp32) ----------------

__global__ void k_deg_init(float* __restrict__ deg, int n) {
    int i = blockIdx.x * BLK + threadIdx.x;
    if (i < n) deg[i] = 1.0f;
}
__global__ void k_deg_count(const int* __restrict__ dst, float* __restrict__ deg, int e) {
    int i = blockIdx.x * BLK + threadIdx.x;
    if (i < e) atomicAdd(&deg[dst[i]], 1.0f);
}
__global__ void k_deg_rsqrt(float* __restrict__ deg, int n) {
    int i = blockIdx.x * BLK + threadIdx.x;
    if (i < n) deg[i] = rsqrtf(deg[i]);
}
template <int C, bool RELU_IN, bool BIAS>
__global__ void k_selfloop(const float* __restrict__ h, const float* __restrict__ dis,
                           const float* __restrict__ b, float* __restrict__ agg, int n) {
    int t = blockIdx.x * BLK + threadIdx.x;
    int node = t / C, c = t % C;
    if (node >= n) return;
    float w = dis[node];
    float v = h[t];
    if (RELU_IN) v = fmaxf(v, 0.0f);
    agg[t] = (BIAS ? b[c] : 0.0f) + v * w * w;
}
template <int C, bool RELU_IN>
__global__ void k_scatter(const int* __restrict__ src, const int* __restrict__ dst,
                          const float* __restrict__ h, const float* __restrict__ dis,
                          float* __restrict__ agg, int e) {
    int t = blockIdx.x * BLK + threadIdx.x;
    int edge = t / C, c = t % C;
    if (edge >= e) return;
    int s = src[edge], d = dst[edge];
    float w = dis[s] * dis[d];
    float v = h[(size_t)s * C + c];
    if (RELU_IN) v = fmaxf(v, 0.0f);
    atomicAdd(&agg[(size_t)d * C + c], v * w);
}
__global__ void k_zero(float* __restrict__ out) { out[0] = 0.0f; }
__global__ void k_final(const float* __restrict__ h, const float* __restrict__ Wfc,
                        const float* __restrict__ bfc, float* __restrict__ out, int n,
                        float inv_n) {
    int i = blockIdx.x * BLK + threadIdx.x;
    float v = 0.0f;
    if (i < n) {
        float acc = bfc[0];
        const float* row = h + (size_t)i * 16;
#pragma unroll
        for (int c = 0; c < 16; ++c) acc = fmaf(fmaxf(row[c], 0.0f), Wfc[c], acc);
        v = acc;
    }
#pragma unroll
    for (int off = 32; off > 0; off >>= 1) v += __shfl_down(v, off);
    __shared__ float sw[BLK / 64];
    int wid = threadIdx.x >> 6;
    if ((threadIdx.x & 63) == 0) sw[wid] = v;
    __syncthreads();
    if (threadIdx.x == 0) {
        float t = 0.0f;
#pragma unroll
        for (int w = 0; w < BLK / 64; ++w) t += sw[w];
        atomicAdd(out, t * inv_n);
    }
}

// ---------------- launch ----------------

extern "C" void kernel_launch(void* const* d_in, const int* in_sizes, int n_in,
                              void* d_out, int out_size, void* d_ws, size_t ws_size,
                              hipStream_t stream) {
    const float* x   = (const float*)d_in[0];
    const int* ei    = (const int*)d_in[1];   // integer inputs delivered as int32
    const float* W1  = (const float*)d_in[2];
    const float* b1  = (const float*)d_in[3];
    const float* W2  = (const float*)d_in[4];
    const float* b2  = (const float*)d_in[5];
    const float* W3  = (const float*)d_in[6];
    const float* b3  = (const float*)d_in[7];
    const float* Wfc = (const float*)d_in[8];
    const float* bfc = (const float*)d_in[9];
    float* out = (float*)d_out;

    const int n = in_sizes[0] / 32;
    const int e = in_sizes[1] / 2;
    const int* src = ei;
    const int* dst = ei + e;

    auto g1 = [](long long work) { return dim3((unsigned)((work + BLK - 1) / BLK)); };
    auto gA = [](long long work) { return dim3((unsigned)((work + BLKA - 1) / BLKA)); };

    const int NB   = (n + BNODES - 1) >> BSHIFT;        // dst buckets
    const int NBLK = (e + CHUNK - 1) / CHUNK;           // hist/bin blocks
    const long long L = (long long)NB * NBLK;           // histogram size
    const int P = (int)((L + BLK - 1) / BLK);           // scan partials
    const int PM = (int)(((long long)n * 4 + BLKA - 1) / BLKA);  // mean partial blocks

    auto align_up = [](size_t v) { return (v + 255) & ~(size_t)255; };
    size_t off = 0;
    auto carve = [&](size_t bytes) { size_t o = off; off += align_up(bytes); return o; };
    char* base = (char*)d_ws;
    size_t o_dis   = carve((size_t)n * 4);
    size_t o_noff  = carve(((size_t)n + 1) * 4);
    size_t o_ghist = carve((size_t)L * 4);
    size_t o_goff  = carve((size_t)L * 4);
    size_t o_part  = carve(((size_t)P + 1) * 4);
    size_t o_pm    = carve((size_t)PM * 4);
    size_t o_A     = carve((size_t)n * 16 * 2);
    size_t o_B     = carve((size_t)n * 16 * 2);
    size_t o_keys  = carve((size_t)e * 4);
    size_t o_sort  = carve((size_t)e * 4);
    bool ok = (off <= ws_size) && (NB <= MAXNB) && (n < (1 << 20));

    if (ok) {
        float* dis  = (float*)(base + o_dis);
        int* noff   = (int*)(base + o_noff);
        int* ghist  = (int*)(base + o_ghist);
        int* goff   = (int*)(base + o_goff);
        int* part   = (int*)(base + o_part);
        float* pm   = (float*)(base + o_pm);
        unsigned* A = (unsigned*)(base + o_A);
        unsigned* B = (unsigned*)(base + o_B);
        unsigned int* keys   = (unsigned int*)(base + o_keys);
        unsigned int* sorted = (unsigned int*)(base + o_sort);

        // build: hist -> scan -> bin -> per-bucket sort (+ node offsets + dis)
        k_hist<<<dim3(NBLK), BLK, 0, stream>>>(dst, ghist, e, NB, NBLK);
        k_scan1<<<g1(L), BLK, 0, stream>>>(ghist, goff, part, (int)L);
        k_scan2<<<1, 1024, 0, stream>>>(part, P);
        k_scan3<<<g1(L), BLK, 0, stream>>>(goff, part, (int)L);
        k_bin<<<dim3(NBLK), BLK, 0, stream>>>(src, dst, goff, keys, e, NB, NBLK);
        k_sortb<<<dim3(NB), BLK, 0, stream>>>(keys, goff, sorted, noff, dis, n, NB, NBLK, e);

        // L1: A = pack-bf16((x@W1)*dis)
        k_transform1_bf<<<g1((long long)n * 8), BLK, 0, stream>>>(x, W1, dis, A, n);
        // L1 agg: B = pack(dis*relu(b1 + dis*sum))
        k_agg<0><<<gA((long long)n * 4), BLKA, 0, stream>>>(A, dis, b1, nullptr, nullptr, nullptr, nullptr, nullptr,
                                                            sorted, noff, B, n);
        // L2 agg + fused L2/L3 transforms
        k_agg<1><<<gA((long long)n * 4), BLKA, 0, stream>>>(B, dis, nullptr, W2, b2, W3, nullptr, nullptr,
                                                            sorted, noff, A, n);
        // L3 agg + fused FC -> per-block partials -> deterministic reduce
        k_agg<2><<<gA((long long)n * 4), BLKA, 0, stream>>>(A, dis, b3, nullptr, nullptr, nullptr, Wfc, bfc,
                                                            sorted, noff, pm, n);
        k_reduce<<<1, BLK, 0, stream>>>(pm, PM, out, 1.0f / (float)n);
    } else {
        // fallback: atomic scatter path (fp32)
        float* dis = (float*)d_ws;
        float* A = dis + (((size_t)n + 255) & ~(size_t)255);
        float* B = A + (size_t)n * 32;

        k_deg_init<<<g1(n), BLK, 0, stream>>>(dis, n);
        k_deg_count<<<g1(e), BLK, 0, stream>>>(dst, dis, e);
        k_deg_rsqrt<<<g1(n), BLK, 0, stream>>>(dis, n);

        k_transform<32, 16, false, false, false><<<g1((long long)n * 16), BLK, 0, stream>>>(x, W1, nullptr, nullptr, A, n);
        k_selfloop<16, false, true><<<g1((long long)n * 16), BLK, 0, stream>>>(A, dis, b1, B, n);
        k_scatter<16, false><<<g1((long long)e * 16), BLK, 0, stream>>>(src, dst, A, dis, B, e);

        k_selfloop<16, true, false><<<g1((long long)n * 16), BLK, 0, stream>>>(B, dis, nullptr, A, n);
        k_scatter<16, true><<<g1((long long)e * 16), BLK, 0, stream>>>(src, dst, B, dis, A, e);
        k_transform<16, 32, true, true, false><<<g1((long long)n * 32), BLK, 0, stream>>>(A, W2, b2, nullptr, B, n);

        k_transform<32, 16, false, false, false><<<g1((long long)n * 16), BLK, 0, stream>>>(B, W3, nullptr, nullptr, A, n);
        k_selfloop<16, false, true><<<g1((long long)n * 16), BLK, 0, stream>>>(A, dis, b3, B, n);
        k_scatter<16, false><<<g1((long long)e * 16), BLK, 0, stream>>>(src, dst, A, dis, B, e);

        k_zero<<<1, 1, 0, stream>>>(out);
        k_final<<<g1(n), BLK, 0, stream>>>(B, Wfc, bfc, out, n, 1.0f / (float)n);
    }
}

// Round 15
// 180.359 us; speedup vs baseline: 1.6098x; 1.1832x over previous
//
#include <hip/hip_runtime.h>

static constexpr int BLK = 256;
static constexpr int BLKA = 128;     // k_agg block size
static constexpr int CHUNK = 4096;   // edges per hist/bin block
static constexpr int BSHIFT = 7;     // 128 dst-nodes per bucket
static constexpr int BNODES = 128;
static constexpr int MAXNB = 1024;

__device__ __forceinline__ float bf_lo(unsigned u) { return __uint_as_float(u << 16); }
__device__ __forceinline__ float bf_hi(unsigned u) { return __uint_as_float(u & 0xFFFF0000u); }
__device__ __forceinline__ unsigned bf_r(float f) {
    unsigned x = __float_as_uint(f);
    x += 0x7fffu + ((x >> 16) & 1u);   // round-to-nearest-even
    return x >> 16;
}
__device__ __forceinline__ unsigned bf_pack(float lo, float hi) {
    return bf_r(lo) | (bf_r(hi) << 16);
}

// ---------------- bucket build ----------------

__global__ __launch_bounds__(BLK) void k_hist(const int* __restrict__ dst, int* __restrict__ ghist,
                                              int e, int NB, int NBLK) {
    __shared__ int h[MAXNB];
    for (int i = threadIdx.x; i < NB; i += BLK) h[i] = 0;
    __syncthreads();
    int base = blockIdx.x * CHUNK;
    int lim = min(e - base, CHUNK);
    bool v4 = ((((size_t)(dst + base)) & 15) == 0);
    if (v4 && lim == CHUNK) {
        const int4* d4 = (const int4*)(dst + base);
        for (int q = threadIdx.x; q < CHUNK / 4; q += BLK) {
            int4 v = d4[q];
            atomicAdd(&h[v.x >> BSHIFT], 1);
            atomicAdd(&h[v.y >> BSHIFT], 1);
            atomicAdd(&h[v.z >> BSHIFT], 1);
            atomicAdd(&h[v.w >> BSHIFT], 1);
        }
    } else {
        for (int r = threadIdx.x; r < lim; r += BLK) atomicAdd(&h[dst[base + r] >> BSHIFT], 1);
    }
    __syncthreads();
    for (int b = threadIdx.x; b < NB; b += BLK) ghist[b * NBLK + blockIdx.x] = h[b];
}

__global__ void k_scan1(const int* __restrict__ in, int* __restrict__ excl,
                        int* __restrict__ partials, int n) {
    __shared__ int s[BLK];
    int i = blockIdx.x * BLK + threadIdx.x;
    int v = (i < n) ? in[i] : 0;
    s[threadIdx.x] = v;
    __syncthreads();
    for (int off = 1; off < BLK; off <<= 1) {
        int t = ((int)threadIdx.x >= off) ? s[threadIdx.x - off] : 0;
        __syncthreads();
        s[threadIdx.x] += t;
        __syncthreads();
    }
    if (i < n) excl[i] = s[threadIdx.x] - v;
    if (threadIdx.x == BLK - 1) partials[blockIdx.x] = s[BLK - 1];
}

__global__ void k_scan2(int* __restrict__ partials, int P) {
    __shared__ int s[1024];
    int carry = 0;
    for (int base = 0; base < P; base += 1024) {
        int i = base + (int)threadIdx.x;
        int v = (i < P) ? partials[i] : 0;
        s[threadIdx.x] = v;
        __syncthreads();
        for (int off = 1; off < 1024; off <<= 1) {
            int t = ((int)threadIdx.x >= off) ? s[threadIdx.x - off] : 0;
            __syncthreads();
            s[threadIdx.x] += t;
            __syncthreads();
        }
        if (i < P) partials[i] = carry + s[threadIdx.x] - v;
        carry += s[1023];
        __syncthreads();
    }
}

// LDS-staged multisplit: bin edges by dst bucket, coalesced run writes.
// Global offsets folded: base(b) = goff[b*NBLK+bid] + part[idx>>8] (scan3 eliminated).
// key = src | (dst&127)<<20   (requires n < 2^20)
__global__ __launch_bounds__(BLK) void k_bin(const int* __restrict__ src, const int* __restrict__ dst,
                                             const int* __restrict__ goff, const int* __restrict__ part,
                                             unsigned int* __restrict__ keys,
                                             int e, int NB, int NBLK) {
    __shared__ int hcur[MAXNB];
    __shared__ int sstart[MAXNB + 1];
    __shared__ int gbase[MAXNB];
    __shared__ unsigned int stage[CHUNK];
    __shared__ unsigned short bkt[CHUNK];
    for (int i = threadIdx.x; i < NB; i += BLK) {
        hcur[i] = 0;
        int idx = i * NBLK + blockIdx.x;
        gbase[i] = goff[idx] + part[idx >> 8];
    }
    __syncthreads();
    int base = blockIdx.x * CHUNK;
    int lim = min(e - base, CHUNK);
    bool v4 = ((((size_t)(dst + base)) & 15) == 0) && ((((size_t)(src + base)) & 15) == 0) && (lim == CHUNK);
    if (v4) {
        const int4* d4 = (const int4*)(dst + base);
        for (int q = threadIdx.x; q < CHUNK / 4; q += BLK) {
            int4 v = d4[q];
            atomicAdd(&hcur[v.x >> BSHIFT], 1);
            atomicAdd(&hcur[v.y >> BSHIFT], 1);
            atomicAdd(&hcur[v.z >> BSHIFT], 1);
            atomicAdd(&hcur[v.w >> BSHIFT], 1);
        }
    } else {
        for (int r = threadIdx.x; r < lim; r += BLK) atomicAdd(&hcur[dst[base + r] >> BSHIFT], 1);
    }
    __syncthreads();
    for (int i = threadIdx.x; i < MAXNB; i += BLK) sstart[i] = (i < NB) ? hcur[i] : 0;
    __syncthreads();
    for (int off = 1; off < MAXNB; off <<= 1) {
        int tv[MAXNB / BLK];
#pragma unroll
        for (int j = 0; j < MAXNB / BLK; ++j) {
            int i = (int)threadIdx.x + j * BLK;
            tv[j] = (i >= off) ? sstart[i - off] : 0;
        }
        __syncthreads();
#pragma unroll
        for (int j = 0; j < MAXNB / BLK; ++j) sstart[(int)threadIdx.x + j * BLK] += tv[j];
        __syncthreads();
    }
    int ex[MAXNB / BLK];
#pragma unroll
    for (int j = 0; j < MAXNB / BLK; ++j) {
        int i = (int)threadIdx.x + j * BLK;
        ex[j] = sstart[i] - ((i < NB) ? hcur[i] : 0);
    }
    __syncthreads();
#pragma unroll
    for (int j = 0; j < MAXNB / BLK; ++j) {
        int i = (int)threadIdx.x + j * BLK;
        sstart[i] = ex[j];
        if (i < NB) hcur[i] = ex[j];
    }
    __syncthreads();
    if (v4) {
        const int4* s4 = (const int4*)(src + base);
        const int4* d4 = (const int4*)(dst + base);
        for (int q = threadIdx.x; q < CHUNK / 4; q += BLK) {
            int4 sv = s4[q];
            int4 dv = d4[q];
#pragma unroll
            for (int u = 0; u < 4; ++u) {
                int s = (u == 0) ? sv.x : (u == 1) ? sv.y : (u == 2) ? sv.z : sv.w;
                int d = (u == 0) ? dv.x : (u == 1) ? dv.y : (u == 2) ? dv.z : dv.w;
                int b = d >> BSHIFT;
                int pos = atomicAdd(&hcur[b], 1);
                stage[pos] = (unsigned)s | ((unsigned)(d & (BNODES - 1)) << 20);
                bkt[pos] = (unsigned short)b;
            }
        }
    } else {
        for (int r = threadIdx.x; r < lim; r += BLK) {
            int s = src[base + r], d = dst[base + r];
            int b = d >> BSHIFT;
            int pos = atomicAdd(&hcur[b], 1);
            stage[pos] = (unsigned)s | ((unsigned)(d & (BNODES - 1)) << 20);
            bkt[pos] = (unsigned short)b;
        }
    }
    __syncthreads();
    for (int j = threadIdx.x; j < lim; j += BLK) {
        int b = bkt[j];
        keys[gbase[b] + (j - sstart[b])] = stage[j];
    }
}

// per-bucket: node degrees -> dis + node offsets; counting-sort keys -> dst-sorted src CSR
__global__ __launch_bounds__(BLK) void k_sortb(const unsigned int* __restrict__ keys,
                                               const int* __restrict__ goff, const int* __restrict__ part,
                                               unsigned int* __restrict__ sorted,
                                               int* __restrict__ node_off, float* __restrict__ dis,
                                               int n, int NB, int NBLK, int e) {
    __shared__ int cnt[BNODES];
    __shared__ int sc[BNODES];
    __shared__ int cur[BNODES];
    int b = blockIdx.x;
    int i0 = b * NBLK;
    int start = goff[i0] + part[i0 >> 8];
    int end;
    if (b + 1 < NB) {
        int i1 = (b + 1) * NBLK;
        end = goff[i1] + part[i1 >> 8];
    } else {
        end = e;
    }
    if (threadIdx.x < BNODES) cnt[threadIdx.x] = 0;
    __syncthreads();
    int astart = (start + 3) & ~3;
    if (astart > end) astart = end;
    int nq = (end - astart) >> 2;
    for (int k = start + (int)threadIdx.x; k < astart; k += BLK) atomicAdd(&cnt[keys[k] >> 20], 1);
    {
        const uint4* k4 = (const uint4*)(keys + astart);
        for (int q = threadIdx.x; q < nq; q += BLK) {
            uint4 v = k4[q];
            atomicAdd(&cnt[v.x >> 20], 1);
            atomicAdd(&cnt[v.y >> 20], 1);
            atomicAdd(&cnt[v.z >> 20], 1);
            atomicAdd(&cnt[v.w >> 20], 1);
        }
    }
    for (int k = astart + (nq << 2) + (int)threadIdx.x; k < end; k += BLK) atomicAdd(&cnt[keys[k] >> 20], 1);
    __syncthreads();
    if (threadIdx.x < BNODES) sc[threadIdx.x] = cnt[threadIdx.x];
    __syncthreads();
    for (int off = 1; off < BNODES; off <<= 1) {
        int v = ((int)threadIdx.x < BNODES && (int)threadIdx.x >= off) ? sc[threadIdx.x - off] : 0;
        __syncthreads();
        if ((int)threadIdx.x < BNODES) sc[threadIdx.x] += v;
        __syncthreads();
    }
    if ((int)threadIdx.x < BNODES) {
        int excl = sc[threadIdx.x] - cnt[threadIdx.x];
        cur[threadIdx.x] = start + excl;
        int d = b * BNODES + (int)threadIdx.x;
        if (d < n) {
            node_off[d] = start + excl;
            dis[d] = rsqrtf(1.0f + (float)cnt[threadIdx.x]);
        }
    }
    if (b == NB - 1 && threadIdx.x == 0) node_off[n] = e;
    __syncthreads();
    for (int k = start + (int)threadIdx.x; k < astart; k += BLK) {
        unsigned key = keys[k];
        int pos = atomicAdd(&cur[key >> 20], 1);
        sorted[pos] = key & 0xFFFFFu;
    }
    {
        const uint4* k4 = (const uint4*)(keys + astart);
        for (int q = threadIdx.x; q < nq; q += BLK) {
            uint4 v = k4[q];
#pragma unroll
            for (int u = 0; u < 4; ++u) {
                unsigned key = (u == 0) ? v.x : (u == 1) ? v.y : (u == 2) ? v.z : v.w;
                int pos = atomicAdd(&cur[key >> 20], 1);
                sorted[pos] = key & 0xFFFFFu;
            }
        }
    }
    for (int k = astart + (nq << 2) + (int)threadIdx.x; k < end; k += BLK) {
        unsigned key = keys[k];
        int pos = atomicAdd(&cur[key >> 20], 1);
        sorted[pos] = key & 0xFFFFFu;
    }
}

// ---------------- dense transforms ----------------

// fp32-out variant (fallback path)
template <int CIN, int COUT, bool BIAS, bool RELU_OUT, bool SCALE_OUT>
__global__ void k_transform(const float* __restrict__ in, const float* __restrict__ W,
                            const float* __restrict__ bias, const float* __restrict__ dis,
                            float* __restrict__ out, int n) {
    int t = blockIdx.x * BLK + threadIdx.x;
    int node = t / COUT, c = t % COUT;
    if (node >= n) return;
    const float* row = in + (size_t)node * CIN;
    float acc = BIAS ? bias[c] : 0.0f;
#pragma unroll
    for (int k = 0; k < CIN; ++k) acc = fmaf(row[k], W[k * COUT + c], acc);
    if (RELU_OUT) acc = fmaxf(acc, 0.0f);
    if (SCALE_OUT) acc *= dis[node];
    out[t] = acc;
}

// packed-bf16 L1 transform: word j of node = channels 2j,2j+1 of (x@W1)*dis
__global__ void k_transform1_bf(const float* __restrict__ in, const float* __restrict__ W,
                                const float* __restrict__ dis, unsigned* __restrict__ out, int n) {
    int t = blockIdx.x * BLK + threadIdx.x;
    int node = t >> 3, j = t & 7;
    if (node >= n) return;
    const float* row = in + (size_t)node * 32;
    float a0 = 0.0f, a1 = 0.0f;
#pragma unroll
    for (int k = 0; k < 32; ++k) {
        float v = row[k];
        a0 = fmaf(v, W[k * 16 + 2 * j], a0);
        a1 = fmaf(v, W[k * 16 + 2 * j + 1], a1);
    }
    float sd = dis[node];
    out[t] = bf_pack(a0 * sd, a1 * sd);
}

// ---------------- fused gather aggregation (4 lanes/node, uint2 gathers, 16-deep MLP) ----
// lane j (0..3) holds channels 4j..4j+3. Per edge: one 32B coalesced random L2 request —
// the structural floor is E/(8 XCD x ~4 req/cy x 2.4GHz) ~= 42us per aggregation.
// WMODE 0: out = pack( dis*relu(b1 + dis*acc) )
// WMODE 1: out = pack( dis * ((relu((dis*acc)@W2 + b2)) @ W3) )
// WMODE 2: h3 = b3 + dis*acc; partials[block] = sum relu(h3)@Wfc + bfc   (no atomics)
template <int WMODE>
__global__ __launch_bounds__(BLKA) void k_agg(const unsigned* __restrict__ in, const float* __restrict__ dis,
                                              const float* __restrict__ bias,
                                              const float* __restrict__ W2, const float* __restrict__ b2,
                                              const float* __restrict__ W3,
                                              const float* __restrict__ Wfc, const float* __restrict__ bfc,
                                              const unsigned int* __restrict__ sorted,
                                              const int* __restrict__ node_off,
                                              void* __restrict__ outv, int n) {
    int t = blockIdx.x * BLKA + threadIdx.x;
    int d = t >> 2, j = t & 3;
    bool valid = d < n;
    int dd = valid ? d : 0;
    int k = node_off[dd], end = node_off[dd + 1];
    if (!valid) end = k;
    const uint2* inrow = (const uint2*)in;   // row s starts at uint2 index (s<<2)
    uint2 zz; zz.x = 0u; zz.y = 0u;
    uint2 ws = valid ? inrow[((size_t)dd << 2) + j] : zz;   // self-loop term
    float a00 = bf_lo(ws.x), a10 = bf_hi(ws.x), a20 = bf_lo(ws.y), a30 = bf_hi(ws.y);
    float a01 = 0.0f, a11 = 0.0f, a21 = 0.0f, a31 = 0.0f;
    // peel to 16B alignment of sorted+k
    for (; k < end && (k & 3); ++k) {
        uint2 w = inrow[((size_t)sorted[k] << 2) + j];
        a00 += bf_lo(w.x); a10 += bf_hi(w.x); a20 += bf_lo(w.y); a30 += bf_hi(w.y);
    }
    // 16-edge main loop: all 16 gathers in flight before first consume
    for (; k + 15 < end; k += 16) {
        uint4 i0 = *(const uint4*)(sorted + k);
        uint4 i1 = *(const uint4*)(sorted + k + 4);
        uint4 i2 = *(const uint4*)(sorted + k + 8);
        uint4 i3 = *(const uint4*)(sorted + k + 12);
        uint2 w0 = inrow[((size_t)i0.x << 2) + j];
        uint2 w1 = inrow[((size_t)i0.y << 2) + j];
        uint2 w2 = inrow[((size_t)i0.z << 2) + j];
        uint2 w3 = inrow[((size_t)i0.w << 2) + j];
        uint2 w4 = inrow[((size_t)i1.x << 2) + j];
        uint2 w5 = inrow[((size_t)i1.y << 2) + j];
        uint2 w6 = inrow[((size_t)i1.z << 2) + j];
        uint2 w7 = inrow[((size_t)i1.w << 2) + j];
        uint2 w8 = inrow[((size_t)i2.x << 2) + j];
        uint2 w9 = inrow[((size_t)i2.y << 2) + j];
        uint2 wa = inrow[((size_t)i2.z << 2) + j];
        uint2 wb = inrow[((size_t)i2.w << 2) + j];
        uint2 wc = inrow[((size_t)i3.x << 2) + j];
        uint2 wd = inrow[((size_t)i3.y << 2) + j];
        uint2 we = inrow[((size_t)i3.z << 2) + j];
        uint2 wf = inrow[((size_t)i3.w << 2) + j];
        a00 += (bf_lo(w0.x) + bf_lo(w2.x)) + (bf_lo(w4.x) + bf_lo(w6.x));
        a01 += (bf_lo(w1.x) + bf_lo(w3.x)) + (bf_lo(w5.x) + bf_lo(w7.x));
        a10 += (bf_hi(w0.x) + bf_hi(w2.x)) + (bf_hi(w4.x) + bf_hi(w6.x));
        a11 += (bf_hi(w1.x) + bf_hi(w3.x)) + (bf_hi(w5.x) + bf_hi(w7.x));
        a20 += (bf_lo(w0.y) + bf_lo(w2.y)) + (bf_lo(w4.y) + bf_lo(w6.y));
        a21 += (bf_lo(w1.y) + bf_lo(w3.y)) + (bf_lo(w5.y) + bf_lo(w7.y));
        a30 += (bf_hi(w0.y) + bf_hi(w2.y)) + (bf_hi(w4.y) + bf_hi(w6.y));
        a31 += (bf_hi(w1.y) + bf_hi(w3.y)) + (bf_hi(w5.y) + bf_hi(w7.y));
        a00 += (bf_lo(w8.x) + bf_lo(wa.x)) + (bf_lo(wc.x) + bf_lo(we.x));
        a01 += (bf_lo(w9.x) + bf_lo(wb.x)) + (bf_lo(wd.x) + bf_lo(wf.x));
        a10 += (bf_hi(w8.x) + bf_hi(wa.x)) + (bf_hi(wc.x) + bf_hi(we.x));
        a11 += (bf_hi(w9.x) + bf_hi(wb.x)) + (bf_hi(wd.x) + bf_hi(wf.x));
        a20 += (bf_lo(w8.y) + bf_lo(wa.y)) + (bf_lo(wc.y) + bf_lo(we.y));
        a21 += (bf_lo(w9.y) + bf_lo(wb.y)) + (bf_lo(wd.y) + bf_lo(wf.y));
        a30 += (bf_hi(w8.y) + bf_hi(wa.y)) + (bf_hi(wc.y) + bf_hi(we.y));
        a31 += (bf_hi(w9.y) + bf_hi(wb.y)) + (bf_hi(wd.y) + bf_hi(wf.y));
    }
    for (; k + 7 < end; k += 8) {
        uint4 i0 = *(const uint4*)(sorted + k);
        uint4 i1 = *(const uint4*)(sorted + k + 4);
        uint2 w0 = inrow[((size_t)i0.x << 2) + j];
        uint2 w1 = inrow[((size_t)i0.y << 2) + j];
        uint2 w2 = inrow[((size_t)i0.z << 2) + j];
        uint2 w3 = inrow[((size_t)i0.w << 2) + j];
        uint2 w4 = inrow[((size_t)i1.x << 2) + j];
        uint2 w5 = inrow[((size_t)i1.y << 2) + j];
        uint2 w6 = inrow[((size_t)i1.z << 2) + j];
        uint2 w7 = inrow[((size_t)i1.w << 2) + j];
        a00 += (bf_lo(w0.x) + bf_lo(w2.x)) + (bf_lo(w4.x) + bf_lo(w6.x));
        a01 += (bf_lo(w1.x) + bf_lo(w3.x)) + (bf_lo(w5.x) + bf_lo(w7.x));
        a10 += (bf_hi(w0.x) + bf_hi(w2.x)) + (bf_hi(w4.x) + bf_hi(w6.x));
        a11 += (bf_hi(w1.x) + bf_hi(w3.x)) + (bf_hi(w5.x) + bf_hi(w7.x));
        a20 += (bf_lo(w0.y) + bf_lo(w2.y)) + (bf_lo(w4.y) + bf_lo(w6.y));
        a21 += (bf_lo(w1.y) + bf_lo(w3.y)) + (bf_lo(w5.y) + bf_lo(w7.y));
        a30 += (bf_hi(w0.y) + bf_hi(w2.y)) + (bf_hi(w4.y) + bf_hi(w6.y));
        a31 += (bf_hi(w1.y) + bf_hi(w3.y)) + (bf_hi(w5.y) + bf_hi(w7.y));
    }
    for (; k < end; ++k) {
        uint2 w = inrow[((size_t)sorted[k] << 2) + j];
        a00 += bf_lo(w.x); a10 += bf_hi(w.x); a20 += bf_lo(w.y); a30 += bf_hi(w.y);
    }
    float sd = dis[dd];
    float a0 = (a00 + a01) * sd;   // channel 4j
    float a1 = (a10 + a11) * sd;   // channel 4j+1
    float a2 = (a20 + a21) * sd;   // channel 4j+2
    float a3 = (a30 + a31) * sd;   // channel 4j+3

    if (WMODE == 0) {
        uint2* out = (uint2*)outv;
        if (valid) {
            uint2 r;
            r.x = bf_pack(sd * fmaxf(bias[4 * j] + a0, 0.0f), sd * fmaxf(bias[4 * j + 1] + a1, 0.0f));
            r.y = bf_pack(sd * fmaxf(bias[4 * j + 2] + a2, 0.0f), sd * fmaxf(bias[4 * j + 3] + a3, 0.0f));
            out[((size_t)d << 2) + j] = r;
        }
    } else if (WMODE == 1) {
        // h2[32] = relu(A2@W2 + b2); lane j holds h2[j+4p], p=0..7
        float hh[8];
#pragma unroll
        for (int p = 0; p < 8; ++p) hh[p] = b2[j + 4 * p];
#pragma unroll
        for (int kk = 0; kk < 4; ++kk) {
            float r0 = __shfl(a0, kk, 4);   // A2[4kk]
            float r1 = __shfl(a1, kk, 4);   // A2[4kk+1]
            float r2 = __shfl(a2, kk, 4);   // A2[4kk+2]
            float r3 = __shfl(a3, kk, 4);   // A2[4kk+3]
#pragma unroll
            for (int p = 0; p < 8; ++p) {
                int m = j + 4 * p;
                hh[p] = fmaf(r0, W2[(4 * kk) * 32 + m], hh[p]);
                hh[p] = fmaf(r1, W2[(4 * kk + 1) * 32 + m], hh[p]);
                hh[p] = fmaf(r2, W2[(4 * kk + 2) * 32 + m], hh[p]);
                hh[p] = fmaf(r3, W2[(4 * kk + 3) * 32 + m], hh[p]);
            }
        }
#pragma unroll
        for (int p = 0; p < 8; ++p) hh[p] = fmaxf(hh[p], 0.0f);
        float z0 = 0.0f, z1 = 0.0f, z2 = 0.0f, z3 = 0.0f;
#pragma unroll
        for (int kk = 0; kk < 4; ++kk) {
#pragma unroll
            for (int p = 0; p < 8; ++p) {
                float u = __shfl(hh[p], kk, 4);   // h2[kk+4p]
                int m = kk + 4 * p;
                z0 = fmaf(u, W3[m * 16 + 4 * j], z0);
                z1 = fmaf(u, W3[m * 16 + 4 * j + 1], z1);
                z2 = fmaf(u, W3[m * 16 + 4 * j + 2], z2);
                z3 = fmaf(u, W3[m * 16 + 4 * j + 3], z3);
            }
        }
        uint2* out = (uint2*)outv;
        if (valid) {
            uint2 r;
            r.x = bf_pack(z0 * sd, z1 * sd);
            r.y = bf_pack(z2 * sd, z3 * sd);
            out[((size_t)d << 2) + j] = r;
        }
    } else {
        float* partials = (float*)outv;
        float contrib = 0.0f;
        if (valid) {
            contrib = bfc[0] * 0.25f;
            contrib = fmaf(fmaxf(bias[4 * j] + a0, 0.0f), Wfc[4 * j], contrib);
            contrib = fmaf(fmaxf(bias[4 * j + 1] + a1, 0.0f), Wfc[4 * j + 1], contrib);
            contrib = fmaf(fmaxf(bias[4 * j + 2] + a2, 0.0f), Wfc[4 * j + 2], contrib);
            contrib = fmaf(fmaxf(bias[4 * j + 3] + a3, 0.0f), Wfc[4 * j + 3], contrib);
        }
#pragma unroll
        for (int m = 1; m < 64; m <<= 1) contrib += __shfl_xor(contrib, m, 64);
        __shared__ float sw[BLKA / 64];
        if ((threadIdx.x & 63) == 0) sw[threadIdx.x >> 6] = contrib;
        __syncthreads();
        if (threadIdx.x == 0) {
            float tt = 0.0f;
#pragma unroll
            for (int w = 0; w < BLKA / 64; ++w) tt += sw[w];
            partials[blockIdx.x] = tt;
        }
    }
}

// deterministic single-block reduction of partials -> out[0] = sum * inv_n
__global__ __launch_bounds__(BLK) void k_reduce(const float* __restrict__ partials, int P,
                                                float* __restrict__ out, float inv_n) {
    float v = 0.0f;
    for (int i = threadIdx.x; i < P; i += BLK) v += partials[i];
#pragma unroll
    for (int m = 1; m < 64; m <<= 1) v += __shfl_xor(v, m, 64);
    __shared__ float sw[BLK / 64];
    if ((threadIdx.x & 63) == 0) sw[threadIdx.x >> 6] = v;
    __syncthreads();
    if (threadIdx.x == 0) {
        float tt = 0.0f;
#pragma unroll
        for (int w = 0; w < BLK / 64; ++w) tt += sw[w];
        out[0] = tt * inv_n;
    }
}

// ---------------- fallback (atomic scatter, fp32) ----------------

__global__ void k_deg_init(float* __restrict__ deg, int n) {
    int i = blockIdx.x * BLK + threadIdx.x;
    if (i < n) deg[i] = 1.0f;
}
__global__ void k_deg_count(const int* __restrict__ dst, float* __restrict__ deg, int e) {
    int i = blockIdx.x * BLK + threadIdx.x;
    if (i < e) atomicAdd(&deg[dst[i]], 1.0f);
}
__global__ void k_deg_rsqrt(float* __restrict__ deg, int n) {
    int i = blockIdx.x * BLK + threadIdx.x;
    if (i < n) deg[i] = rsqrtf(deg[i]);
}
template <int C, bool RELU_IN, bool BIAS>
__global__ void k_selfloop(const float* __restrict__ h, const float* __restrict__ dis,
                           const float* __restrict__ b, float* __restrict__ agg, int n) {
    int t = blockIdx.x * BLK + threadIdx.x;
    int node = t / C, c = t % C;
    if (node >= n) return;
    float w = dis[node];
    float v = h[t];
    if (RELU_IN) v = fmaxf(v, 0.0f);
    agg[t] = (BIAS ? b[c] : 0.0f) + v * w * w;
}
template <int C, bool RELU_IN>
__global__ void k_scatter(const int* __restrict__ src, const int* __restrict__ dst,
                          const float* __restrict__ h, const float* __restrict__ dis,
                          float* __restrict__ agg, int e) {
    int t = blockIdx.x * BLK + threadIdx.x;
    int edge = t / C, c = t % C;
    if (edge >= e) return;
    int s = src[edge], d = dst[edge];
    float w = dis[s] * dis[d];
    float v = h[(size_t)s * C + c];
    if (RELU_IN) v = fmaxf(v, 0.0f);
    atomicAdd(&agg[(size_t)d * C + c], v * w);
}
__global__ void k_zero(float* __restrict__ out) { out[0] = 0.0f; }
__global__ void k_final(const float* __restrict__ h, const float* __restrict__ Wfc,
                        const float* __restrict__ bfc, float* __restrict__ out, int n,
                        float inv_n) {
    int i = blockIdx.x * BLK + threadIdx.x;
    float v = 0.0f;
    if (i < n) {
        float acc = bfc[0];
        const float* row = h + (size_t)i * 16;
#pragma unroll
        for (int c = 0; c < 16; ++c) acc = fmaf(fmaxf(row[c], 0.0f), Wfc[c], acc);
        v = acc;
    }
#pragma unroll
    for (int off = 32; off > 0; off >>= 1) v += __shfl_down(v, off);
    __shared__ float sw[BLK / 64];
    int wid = threadIdx.x >> 6;
    if ((threadIdx.x & 63) == 0) sw[wid] = v;
    __syncthreads();
    if (threadIdx.x == 0) {
        float t = 0.0f;
#pragma unroll
        for (int w = 0; w < BLK / 64; ++w) t += sw[w];
        atomicAdd(out, t * inv_n);
    }
}

// ---------------- launch ----------------

extern "C" void kernel_launch(void* const* d_in, const int* in_sizes, int n_in,
                              void* d_out, int out_size, void* d_ws, size_t ws_size,
                              hipStream_t stream) {
    const float* x   = (const float*)d_in[0];
    const int* ei    = (const int*)d_in[1];   // integer inputs delivered as int32
    const float* W1  = (const float*)d_in[2];
    const float* b1  = (const float*)d_in[3];
    const float* W2  = (const float*)d_in[4];
    const float* b2  = (const float*)d_in[5];
    const float* W3  = (const float*)d_in[6];
    const float* b3  = (const float*)d_in[7];
    const float* Wfc = (const float*)d_in[8];
    const float* bfc = (const float*)d_in[9];
    float* out = (float*)d_out;

    const int n = in_sizes[0] / 32;
    const int e = in_sizes[1] / 2;
    const int* src = ei;
    const int* dst = ei + e;

    auto g1 = [](long long work) { return dim3((unsigned)((work + BLK - 1) / BLK)); };
    auto gA = [](long long work) { return dim3((unsigned)((work + BLKA - 1) / BLKA)); };

    const int NB   = (n + BNODES - 1) >> BSHIFT;        // dst buckets
    const int NBLK = (e + CHUNK - 1) / CHUNK;           // hist/bin blocks
    const long long L = (long long)NB * NBLK;           // histogram size
    const int P = (int)((L + BLK - 1) / BLK);           // scan partials
    const int PM = (int)(((long long)n * 4 + BLKA - 1) / BLKA);  // mean partial blocks

    auto align_up = [](size_t v) { return (v + 255) & ~(size_t)255; };
    size_t off = 0;
    auto carve = [&](size_t bytes) { size_t o = off; off += align_up(bytes); return o; };
    char* base = (char*)d_ws;
    size_t o_dis   = carve((size_t)n * 4);
    size_t o_noff  = carve(((size_t)n + 1) * 4);
    size_t o_ghist = carve((size_t)L * 4);
    size_t o_goff  = carve((size_t)L * 4);
    size_t o_part  = carve(((size_t)P + 1) * 4);
    size_t o_pm    = carve((size_t)PM * 4);
    size_t o_A     = carve((size_t)n * 16 * 2);
    size_t o_B     = carve((size_t)n * 16 * 2);
    size_t o_keys  = carve((size_t)e * 4);
    size_t o_sort  = carve((size_t)e * 4);
    bool ok = (off <= ws_size) && (NB <= MAXNB) && (n < (1 << 20));

    if (ok) {
        float* dis  = (float*)(base + o_dis);
        int* noff   = (int*)(base + o_noff);
        int* ghist  = (int*)(base + o_ghist);
        int* goff   = (int*)(base + o_goff);
        int* part   = (int*)(base + o_part);
        float* pm   = (float*)(base + o_pm);
        unsigned* A = (unsigned*)(base + o_A);
        unsigned* B = (unsigned*)(base + o_B);
        unsigned int* keys   = (unsigned int*)(base + o_keys);
        unsigned int* sorted = (unsigned int*)(base + o_sort);

        // build: hist -> scan (partials folded into consumers) -> bin -> per-bucket sort
        k_hist<<<dim3(NBLK), BLK, 0, stream>>>(dst, ghist, e, NB, NBLK);
        k_scan1<<<g1(L), BLK, 0, stream>>>(ghist, goff, part, (int)L);
        k_scan2<<<1, 1024, 0, stream>>>(part, P);
        k_bin<<<dim3(NBLK), BLK, 0, stream>>>(src, dst, goff, part, keys, e, NB, NBLK);
        k_sortb<<<dim3(NB), BLK, 0, stream>>>(keys, goff, part, sorted, noff, dis, n, NB, NBLK, e);

        // L1: A = pack-bf16((x@W1)*dis)
        k_transform1_bf<<<g1((long long)n * 8), BLK, 0, stream>>>(x, W1, dis, A, n);
        // L1 agg: B = pack(dis*relu(b1 + dis*sum))
        k_agg<0><<<gA((long long)n * 4), BLKA, 0, stream>>>(A, dis, b1, nullptr, nullptr, nullptr, nullptr, nullptr,
                                                            sorted, noff, B, n);
        // L2 agg + fused L2/L3 transforms
        k_agg<1><<<gA((long long)n * 4), BLKA, 0, stream>>>(B, dis, nullptr, W2, b2, W3, nullptr, nullptr,
                                                            sorted, noff, A, n);
        // L3 agg + fused FC -> per-block partials -> deterministic reduce
        k_agg<2><<<gA((long long)n * 4), BLKA, 0, stream>>>(A, dis, b3, nullptr, nullptr, nullptr, Wfc, bfc,
                                                            sorted, noff, pm, n);
        k_reduce<<<1, BLK, 0, stream>>>(pm, PM, out, 1.0f / (float)n);
    } else {
        // fallback: atomic scatter path (fp32)
        float* dis = (float*)d_ws;
        float* A = dis + (((size_t)n + 255) & ~(size_t)255);
        float* B = A + (size_t)n * 32;

        k_deg_init<<<g1(n), BLK, 0, stream>>>(dis, n);
        k_deg_count<<<g1(e), BLK, 0, stream>>>(dst, dis, e);
        k_deg_rsqrt<<<g1(n), BLK, 0, stream>>>(dis, n);

        k_transform<32, 16, false, false, false><<<g1((long long)n * 16), BLK, 0, stream>>>(x, W1, nullptr, nullptr, A, n);
        k_selfloop<16, false, true><<<g1((long long)n * 16), BLK, 0, stream>>>(A, dis, b1, B, n);
        k_scatter<16, false><<<g1((long long)e * 16), BLK, 0, stream>>>(src, dst, A, dis, B, e);

        k_selfloop<16, true, false><<<g1((long long)n * 16), BLK, 0, stream>>>(B, dis, nullptr, A, n);
        k_scatter<16, true><<<g1((long long)e * 16), BLK, 0, stream>>>(src, dst, B, dis, A, e);
        k_transform<16, 32, true, true, false><<<g1((long long)n * 32), BLK, 0, stream>>>(A, W2, b2, nullptr, B, n);

        k_transform<32, 16, false, false, false><<<g1((long long)n * 16), BLK, 0, stream>>>(B, W3, nullptr, nullptr, A, n);
        k_selfloop<16, false, true><<<g1((long long)n * 16), BLK, 0, stream>>>(A, dis, b3, B, n);
        k_scatter<16, false><<<g1((long long)e * 16), BLK, 0, stream>>>(src, dst, A, dis, B, e);

        k_zero<<<1, 1, 0, stream>>>(out);
        k_final<<<g1(n), BLK, 0, stream>>>(B, Wfc, bfc, out, n, 1.0f / (float)n);
    }
}